// Round 12
// baseline (2903.412 us; speedup 1.0000x reference)
//
#include <hip/hip_runtime.h>
#include <cstdint>
#include <cstddef>

// CMAlign forward. R12: R11 + A-fragment ping-pong prefetch in conv inner loop
// (tap r+1's ds_reads in flight during tap r's MFMAs). Everything else unchanged.
// Shapes: B=64, C=2048, Cq=512, H=24, W=12, HW=288.

namespace {
constexpr int kB    = 64;
constexpr int kHalf = 32;
constexpr int kC    = 2048;
constexpr int kCQ   = 512;
constexpr int kH    = 24;
constexpr int kW    = 12;
constexpr int kHW   = 288;
constexpr float kTemp = 50.0f;
constexpr int kXPlane = 366;  // 16B cells; 5856 B = 96 mod 128 -> kg quadrant offsets
}

typedef __attribute__((ext_vector_type(8))) __bf16 bf16x8;
typedef __attribute__((ext_vector_type(4))) float f32x4;
typedef __attribute__((ext_vector_type(8))) unsigned short ushort8;

__device__ __forceinline__ const float* feat_base(const float* fv, const float* ft, int b) {
  return (b < kHalf) ? (fv + (size_t)b * kC * kHW)
                     : (ft + (size_t)(b - kHalf) * kC * kHW);
}

__device__ __forceinline__ unsigned short f2bf(float f) {
  union { float f; unsigned u; } c; c.f = f;
  unsigned u = c.u;
  unsigned r = (u + 0x7FFFu + ((u >> 16) & 1u)) >> 16;  // RNE
  return (unsigned short)r;
}

__device__ __forceinline__ float bf2f(unsigned short h) {
  union { unsigned u; float f; } c; c.u = ((unsigned)h) << 16;
  return c.f;
}

__device__ __forceinline__ void gload_lds16(const void* g, void* l) {
  __builtin_amdgcn_global_load_lds(
      (const __attribute__((address_space(1))) unsigned int*)g,
      (__attribute__((address_space(3))) unsigned int*)l, 16, 0, 0);
}

__global__ void zero_kernel(float* __restrict__ p, int n) {
  int i = blockIdx.x * 256 + threadIdx.x;
  if (i < n) p[i] = 0.f;
}

// -------- weight prep: w[oc][ic][3][3] fp32 -> MFMA-image wt2 --------
// wt2[chunk64][tap9][fragG32][lane64][j8]; lane = (oc&15) + kg*16, kg=(ic>>3)&3, j=ic&7.
__global__ __launch_bounds__(256) void prep_w_kernel(const float* __restrict__ qw,
                                                     const float* __restrict__ kw,
                                                     unsigned short* __restrict__ wtq,
                                                     unsigned short* __restrict__ wtk) {
  int oc = blockIdx.x;
  int z  = blockIdx.y;
  const float* w = (z ? kw : qw) + (size_t)oc * (kC * 9);
  unsigned short* wt = z ? wtk : wtq;
  __shared__ unsigned short lw[kC * 9];  // [ic][tap]
  int t = threadIdx.x;
#pragma unroll
  for (int it = 0; it < 18; ++it) {
    int i4 = (it * 256 + t) * 4;
    float4 v = *(const float4*)(w + i4);
    lw[i4 + 0] = f2bf(v.x);
    lw[i4 + 1] = f2bf(v.y);
    lw[i4 + 2] = f2bf(v.z);
    lw[i4 + 3] = f2bf(v.w);
  }
  __syncthreads();
  for (int item = t; item < 9 * 256; item += 256) {
    int tap = item >> 8;
    int icb = item & 255;  // ic octet index; ic = icb*8
    ushort8 pk;
#pragma unroll
    for (int j = 0; j < 8; ++j) pk[j] = lw[(icb * 8 + j) * 9 + tap];
    size_t dst16 = (((size_t)(icb >> 2) * 9 + tap) * 32 + (oc >> 4)) * 64
                   + (oc & 15) + (icb & 3) * 16;
    *(ushort8*)(wt + dst16 * 8) = pk;
  }
}

// -------- FUSED MFMA conv: q+k convs, tile M=128(oc) x N=288(pos), K=2048x9 --------
// Shared Xs; Wbuf[2 buf][3 tap][2 conv][8KB] double-buffered per 3-tap group.
// A-frag ping-pong: tap r+1's ds_reads issued before tap r's MFMAs retire.
__global__ __launch_bounds__(512, 1) void conv_fused_kernel(const unsigned short* __restrict__ wtq,
                                                            const unsigned short* __restrict__ wtk,
                                                            const float* __restrict__ qb,
                                                            const float* __restrict__ kb,
                                                            const float* __restrict__ fv,
                                                            const float* __restrict__ ft,
                                                            float* __restrict__ fqo,
                                                            float* __restrict__ fko) {
  __shared__ unsigned short Wbuf[2 * 6 * 4096];   // [buf][slot r*2+cv][frag8][lane64][j8] 98304 B
  __shared__ unsigned short Xs[4 * kXPlane * 8];  // [kg][hp 366][8ic] 23424 B
  int t    = threadIdx.x;
  int lane = t & 63;
  int wid  = t >> 6;
  int l15  = lane & 15, kg = lane >> 4;
  int wm   = wid & 1, wn = wid >> 1;  // 2M x 4N
  // XCD-clustered decode
  int n    = blockIdx.x;
  int xcd  = n & 7;
  int oc0  = (xcd >> 1) * 128;
  int b    = ((xcd & 1) << 5) + (n >> 3);
  int f0   = oc0 >> 4;  // global frag base
  const float* fb = feat_base(fv, ft, b);
  const char* wtqB = (const char*)wtq;
  const char* wtkB = (const char*)wtk;

  // Xs staging descriptors: item = i*512 + t; item = xkg*366 + hp
  int  xoff[3];
  bool xvalid[3], xhas[3];
#pragma unroll
  for (int i = 0; i < 3; ++i) {
    int item = i * 512 + t;
    xhas[i] = item < 4 * kXPlane;
    int xkg = item / kXPlane;
    int hp  = item - xkg * kXPlane;
    int hy = hp / 14, hx = hp - hy * 14;
    int y = hy - 1, x = hx - 1;
    bool v = xhas[i] && hp < 364 && (y >= 0 && y < kH && x >= 0 && x < kW);
    xvalid[i] = v;
    xoff[i] = v ? (xkg * 8) * kHW + y * kW + x : 0;
  }

  // A-frag read byte addrs within an 8KB slot: lane-linear, conflict-free
  int aAddr[4];
#pragma unroll
  for (int fm = 0; fm < 4; ++fm)
    aAddr[fm] = (((wm * 4 + fm) * 64) + lane) * 16;
  // B-frag read byte addrs
  int nfn = (wn < 2) ? 5 : 4;
  int fnb = (wn < 2) ? wn * 5 : 10 + (wn - 2) * 4;
  int bAddr[5];
#pragma unroll
  for (int fi = 0; fi < 5; ++fi) {
    int p = (fnb + fi) * 16 + l15;
    if (p > 287) p = 287;  // only for unused frags
    int y = p / kW, x = p - y * kW;
    bAddr[fi] = kg * (kXPlane * 16) + ((y + 1) * 14 + (x + 1)) * 16;  // + d16 per tap
  }

  f32x4 acc[2][4][5];
#pragma unroll
  for (int cv = 0; cv < 2; ++cv)
#pragma unroll
    for (int fm = 0; fm < 4; ++fm)
#pragma unroll
      for (int fi = 0; fi < 5; ++fi) acc[cv][fm][fi] = (f32x4){0.f, 0.f, 0.f, 0.f};

  char* WsB = (char*)Wbuf;
  char* XsB = (char*)Xs;
  int wavebase = t & ~63;

  // prologue: zero halo/pad X cells ONCE (never rewritten); stage group (0,0) -> buf0
#pragma unroll
  for (int i = 0; i < 3; ++i) {
    if (xhas[i] && !xvalid[i]) {
      ushort8 pk;
#pragma unroll
      for (int j = 0; j < 8; ++j) pk[j] = 0;
      *(ushort8*)(XsB + (size_t)(i * 512 + t) * 16) = pk;
    }
  }
#pragma unroll
  for (int r = 0; r < 3; ++r) {
    size_t g16 = ((size_t)r * 32 + f0 + wid) * 64 + lane;
    gload_lds16(wtqB + g16 * 16, WsB + (size_t)(r * 2 + 0) * 8192 + wavebase * 16);
    gload_lds16(wtkB + g16 * 16, WsB + (size_t)(r * 2 + 1) * 8192 + wavebase * 16);
  }

  int buf = 0;
#pragma unroll 1
  for (int chunk = 0; chunk < 64; ++chunk) {
    int ic0 = chunk * 32;
    // X: load (transient regs) -> cvt -> LDS, valid cells only
    {
      float xv[3][8];
#pragma unroll
      for (int i = 0; i < 3; ++i)
        if (xvalid[i]) {
          const float* s = fb + (size_t)ic0 * kHW + xoff[i];
#pragma unroll
          for (int j = 0; j < 8; ++j) xv[i][j] = s[(size_t)j * kHW];
        }
#pragma unroll
      for (int i = 0; i < 3; ++i) {
        if (!xvalid[i]) continue;
        ushort8 pk;
#pragma unroll
        for (int j = 0; j < 8; ++j) pk[j] = f2bf(xv[i][j]);
        *(ushort8*)(XsB + (size_t)(i * 512 + t) * 16) = pk;
      }
    }
    __syncthreads();  // X visible + prior W staging drained

#pragma unroll 1
    for (int g = 0; g < 3; ++g) {
      // stage next 3-tap group into the other buffer
      bool hn = (g < 2) || (chunk < 63);
      if (hn) {
        int nchunk = (g < 2) ? chunk : chunk + 1;
        int ng     = (g < 2) ? g + 1 : 0;
#pragma unroll
        for (int r = 0; r < 3; ++r) {
          size_t g16 = ((size_t)(nchunk * 9 + ng * 3 + r) * 32 + f0 + wid) * 64 + lane;
          gload_lds16(wtqB + g16 * 16,
                      WsB + (size_t)((buf ^ 1) * 6 + r * 2 + 0) * 8192 + wavebase * 16);
          gload_lds16(wtkB + g16 * 16,
                      WsB + (size_t)((buf ^ 1) * 6 + r * 2 + 1) * 8192 + wavebase * 16);
        }
      }
      // A-frag ping-pong: slot sl=r&1 consumed, slot sl^1 prefetched for r+1
      bf16x8 afp[2][2][4];  // [slot][cv][fm]
#pragma unroll
      for (int cv = 0; cv < 2; ++cv)
#pragma unroll
        for (int fm = 0; fm < 4; ++fm)
          afp[0][cv][fm] =
              *(const bf16x8*)(WsB + (size_t)(buf * 6 + 0 * 2 + cv) * 8192 + aAddr[fm]);
#pragma unroll
      for (int r = 0; r < 3; ++r) {
        int sl = r & 1;
        if (r < 2) {
#pragma unroll
          for (int cv = 0; cv < 2; ++cv)
#pragma unroll
            for (int fm = 0; fm < 4; ++fm)
              afp[sl ^ 1][cv][fm] =
                  *(const bf16x8*)(WsB + (size_t)(buf * 6 + (r + 1) * 2 + cv) * 8192 + aAddr[fm]);
        }
        int tap = g * 3 + r;
        int d16 = ((tap / 3 - 1) * 14 + (tap % 3 - 1)) * 16;
#pragma unroll
        for (int fi = 0; fi < 5; ++fi) {
          if (fi >= nfn) continue;  // wave-uniform
          bf16x8 bb = *(const bf16x8*)(XsB + bAddr[fi] + d16);
#pragma unroll
          for (int cv = 0; cv < 2; ++cv)
#pragma unroll
            for (int fm = 0; fm < 4; ++fm)
              acc[cv][fm][fi] =
                  __builtin_amdgcn_mfma_f32_16x16x32_bf16(afp[sl][cv][fm], bb, acc[cv][fm][fi],
                                                          0, 0, 0);
        }
      }
      __syncthreads();  // all waves done with buf; next staging drained at next barrier
      buf ^= 1;
    }
  }

  // epilogue: C row(oc) = kg*4+reg (+fm*16+wm*64), col(p) = l15 (+frag base)
#pragma unroll
  for (int cv = 0; cv < 2; ++cv) {
    float* outp = cv ? fko : fqo;
    const float* bias = cv ? kb : qb;
#pragma unroll
    for (int fi = 0; fi < 5; ++fi) {
      if (fi >= nfn) continue;
      int p = (fnb + fi) * 16 + l15;
#pragma unroll
      for (int fm = 0; fm < 4; ++fm)
#pragma unroll
        for (int reg = 0; reg < 4; ++reg) {
          int oc = oc0 + wm * 64 + fm * 16 + kg * 4 + reg;
          outp[((size_t)b * kCQ + oc) * kHW + p] = acc[cv][fm][fi][reg] + bias[oc];
        }
    }
  }
}

// -------- warp GEMM via MFMA: W[c,q] = sum_k tgt[c,k]*pr[q,k] + recon + dist^2 --------
__global__ __launch_bounds__(512) void warp_mfma_kernel(const float* __restrict__ fv,
                                                        const float* __restrict__ ft,
                                                        const unsigned short* __restrict__ prb,
                                                        const float* __restrict__ maskp,
                                                        const int* __restrict__ idx,
                                                        float* __restrict__ outp,
                                                        float* __restrict__ dsq,
                                                        int write_out) {
  __shared__ unsigned short AsHi[128 * 32];
  __shared__ unsigned short AsLo[128 * 32];
  __shared__ unsigned short Bs[288 * 32];
  int t    = threadIdx.x;
  int lane = t & 63;
  int wid  = t >> 6;
  int l15  = lane & 15, kg = lane >> 4;
  int wm   = wid >> 1, wn = wid & 1;
  int c0   = blockIdx.x * 128;
  int b    = blockIdx.y;
  int tb   = idx[b];
  const float* tgt = feat_base(fv, ft, tb);
  const float* fb  = feat_base(fv, ft, b);

  int ar = t >> 2, as = t & 3;
  int aslot = as ^ ((ar ^ (ar >> 2)) & 3);
  unsigned short* aDstHi = AsHi + ar * 32 + aslot * 8;
  unsigned short* aDstLo = AsLo + ar * 32 + aslot * 8;

  int aIdx[2];
#pragma unroll
  for (int fm = 0; fm < 2; ++fm) {
    int r = wm * 32 + fm * 16 + l15;
    aIdx[fm] = r * 32 + (kg ^ ((r ^ (r >> 2)) & 3)) * 8;
  }
  int bIdx[9];
#pragma unroll
  for (int fn = 0; fn < 9; ++fn) {
    int q = wn * 144 + fn * 16 + l15;
    bIdx[fn] = q * 32 + (kg ^ ((q ^ (q >> 2)) & 3)) * 8;
  }

  f32x4 acc[2][9];
#pragma unroll
  for (int fm = 0; fm < 2; ++fm)
#pragma unroll
    for (int fn = 0; fn < 9; ++fn) acc[fm][fn] = (f32x4){0.f, 0.f, 0.f, 0.f};

#pragma unroll 1
  for (int chunk = 0; chunk < 9; ++chunk) {
    int k0 = chunk * 32;
    __syncthreads();
    {
      const float* s = tgt + (size_t)(c0 + ar) * kHW + k0 + as * 8;
      float4 v0 = *(const float4*)(s);
      float4 v1 = *(const float4*)(s + 4);
      float xs[8] = {v0.x, v0.y, v0.z, v0.w, v1.x, v1.y, v1.z, v1.w};
      ushort8 hi, lo;
#pragma unroll
      for (int j = 0; j < 8; ++j) {
        unsigned short h = f2bf(xs[j]);
        hi[j] = h;
        lo[j] = f2bf(xs[j] - bf2f(h));
      }
      *(ushort8*)aDstHi = hi;
      *(ushort8*)aDstLo = lo;
    }
#pragma unroll
    for (int i = 0; i < 3; ++i) {
      int item = i * 512 + t;
      if (item < 1152) {
        int q = item >> 2, s = item & 3;
        ushort8 v = *(const ushort8*)(prb + ((size_t)b * kHW + q) * kHW + k0 + s * 8);
        *(ushort8*)(Bs + q * 32 + (s ^ ((q ^ (q >> 2)) & 3)) * 8) = v;
      }
    }
    __syncthreads();
    bf16x8 ah0 = *(const bf16x8*)(AsHi + aIdx[0]);
    bf16x8 al0 = *(const bf16x8*)(AsLo + aIdx[0]);
    bf16x8 ah1 = *(const bf16x8*)(AsHi + aIdx[1]);
    bf16x8 al1 = *(const bf16x8*)(AsLo + aIdx[1]);
#pragma unroll
    for (int fn = 0; fn < 9; ++fn) {
      bf16x8 bb = *(const bf16x8*)(Bs + bIdx[fn]);
      acc[0][fn] = __builtin_amdgcn_mfma_f32_16x16x32_bf16(ah0, bb, acc[0][fn], 0, 0, 0);
      acc[0][fn] = __builtin_amdgcn_mfma_f32_16x16x32_bf16(al0, bb, acc[0][fn], 0, 0, 0);
      acc[1][fn] = __builtin_amdgcn_mfma_f32_16x16x32_bf16(ah1, bb, acc[1][fn], 0, 0, 0);
      acc[1][fn] = __builtin_amdgcn_mfma_f32_16x16x32_bf16(al1, bb, acc[1][fn], 0, 0, 0);
    }
  }

#pragma unroll
  for (int fn = 0; fn < 9; ++fn) {
    int q = wn * 144 + fn * 16 + l15;
    float mj = maskp[b * kHW + q];
    float psum = 0.f;
#pragma unroll
    for (int fm = 0; fm < 2; ++fm) {
#pragma unroll
      for (int reg = 0; reg < 4; ++reg) {
        int c = c0 + wm * 32 + fm * 16 + kg * 4 + reg;
        float fvv = fb[(size_t)c * kHW + q];
        float Wv  = acc[fm][fn][reg];
        float d   = mj * (fvv - Wv) + 1e-6f;
        psum      = fmaf(d, d, psum);
        if (write_out)
          outp[((size_t)b * kC + c) * kHW + q] = mj * Wv + (1.f - mj) * fvv;
      }
    }
    psum += __shfl_xor(psum, 16);
    psum += __shfl_xor(psum, 32);
    if (lane < 16) atomicAdd(&dsq[b * kHW + q], psum);
  }
}

// -------- mask: per-sample min-max normalized channel L2 norm --------
__global__ __launch_bounds__(320) void mask_kernel(const float* __restrict__ fv,
                                                   const float* __restrict__ ft,
                                                   float* __restrict__ mask) {
  int b = blockIdx.x;
  int t = threadIdx.x;
  const float* fb = feat_base(fv, ft, b);
  float n = 0.f;
  if (t < kHW) {
    float s = 0.f;
    for (int c = 0; c < kC; ++c) { float v = fb[(size_t)c * kHW + t]; s += v * v; }
    n = sqrtf(s);
  }
  __shared__ float sh[320];
  sh[t] = (t < kHW) ? n : 3.4e38f;
  __syncthreads();
  float mn;
  {
    float m = 3.4e38f;
    if (t < 64) {
      for (int i = t; i < 320; i += 64) m = fminf(m, sh[i]);
      for (int off = 32; off; off >>= 1) m = fminf(m, __shfl_xor(m, off));
    }
    __syncthreads();
    if (t == 0) sh[0] = m;
    __syncthreads();
    mn = sh[0];
    __syncthreads();
  }
  sh[t] = (t < kHW) ? n : -3.4e38f;
  __syncthreads();
  float mx;
  {
    float m = -3.4e38f;
    if (t < 64) {
      for (int i = t; i < 320; i += 64) m = fmaxf(m, sh[i]);
      for (int off = 32; off; off >>= 1) m = fmaxf(m, __shfl_xor(m, off));
    }
    __syncthreads();
    if (t == 0) sh[0] = m;
    __syncthreads();
    mx = sh[0];
  }
  if (t < kHW) mask[b * kHW + t] = (n - mn) / ((mx - mn) + 1e-12f);
}

// -------- per-(b,pos) inverse L2 norm over projected channels --------
__global__ __launch_bounds__(320) void norminv_kernel(const float* __restrict__ fq,
                                                      const float* __restrict__ fk,
                                                      float* __restrict__ qinv,
                                                      float* __restrict__ kinv) {
  int b = blockIdx.x;
  int z = blockIdx.y;
  const float* src = z ? fk : fq;
  float* dst       = z ? kinv : qinv;
  int t = threadIdx.x;
  if (t >= kHW) return;
  const float* sb = src + (size_t)b * kCQ * kHW;
  float s = 0.f;
  for (int c = 0; c < kCQ; ++c) { float v = sb[(size_t)c * kHW + t]; s += v * v; }
  float n = sqrtf(s);
  dst[b * kHW + t] = 1.f / fmaxf(n, 1e-12f);
}

// -------- sim logits --------
__global__ __launch_bounds__(320) void sim_kernel(const float* __restrict__ fq,
                                                  const float* __restrict__ fk,
                                                  const float* __restrict__ qinv,
                                                  const float* __restrict__ kinv,
                                                  const int* __restrict__ idx,
                                                  float* __restrict__ logits) {
  int b  = blockIdx.y;
  int q0 = blockIdx.x * 32;
  int t  = threadIdx.x;
  if (t >= kHW) return;
  int tb = idx[b];
  const float* fqb = fq + (size_t)b * kCQ * kHW + q0;
  const float* fkb = fk + (size_t)tb * kCQ * kHW;
  float acc[32];
#pragma unroll
  for (int q = 0; q < 32; ++q) acc[q] = 0.f;
#pragma unroll 1
  for (int c = 0; c < kCQ; ++c) {
    float kv = fkb[(size_t)c * kHW + t];
#pragma unroll
    for (int q = 0; q < 32; ++q) acc[q] = fmaf(fqb[(size_t)c * kHW + q], kv, acc[q]);
  }
  float ks = kinv[tb * kHW + t];
#pragma unroll
  for (int q = 0; q < 32; ++q) {
    float lg = kTemp * qinv[b * kHW + q0 + q] * ks * acc[q];
    logits[((size_t)b * kHW + q0 + q) * kHW + t] = lg;
  }
}

// -------- row softmax over k; emits bf16 only --------
__global__ __launch_bounds__(320) void softmax_kernel(const float* __restrict__ pr,
                                                      unsigned short* __restrict__ prb) {
  int row = blockIdx.x;
  int t   = threadIdx.x;
  const float* rp = pr + (size_t)row * kHW;
  float v = (t < kHW) ? rp[t] : -3.4e38f;
  __shared__ float sh[5];
  int wv = t >> 6, l = t & 63;
  float m = v;
  for (int off = 32; off; off >>= 1) m = fmaxf(m, __shfl_xor(m, off));
  if (l == 0) sh[wv] = m;
  __syncthreads();
  if (t == 0) { float mm = sh[0]; for (int i = 1; i < 5; ++i) mm = fmaxf(mm, sh[i]); sh[0] = mm; }
  __syncthreads();
  m = sh[0];
  float e = (t < kHW) ? __expf(v - m) : 0.f;
  float s = e;
  for (int off = 32; off; off >>= 1) s += __shfl_xor(s, off);
  __syncthreads();
  if (l == 0) sh[wv] = s;
  __syncthreads();
  if (t == 0) { float ss = sh[0]; for (int i = 1; i < 5; ++i) ss += sh[i]; sh[0] = ss; }
  __syncthreads();
  s = sh[0];
  if (t < kHW) prb[(size_t)row * kHW + t] = f2bf(e / s);
}

// -------- comask (reads bf16 pr) --------
__global__ __launch_bounds__(320) void comask_kernel(const unsigned short* __restrict__ prb,
                                                     const float* __restrict__ mask,
                                                     const int* __restrict__ idx,
                                                     float* __restrict__ comask) {
  int b = blockIdx.x;
  int t = threadIdx.x;
  int tb = idx[b];
  __shared__ float mt[kHW];
  __shared__ float cm[kHW];
  __shared__ float red[320];
  if (t < kHW) mt[t] = mask[tb * kHW + t];
  __syncthreads();
  int wv = t >> 6, l = t & 63;
  for (int q = wv; q < kHW; q += 5) {
    const unsigned short* prow = prb + ((size_t)b * kHW + q) * kHW;
    float s = 0.f;
    for (int k = l; k < kHW; k += 64) s += bf2f(prow[k]) * mt[k];
    for (int off = 32; off; off >>= 1) s += __shfl_xor(s, off);
    if (l == 0) cm[q] = mask[b * kHW + q] * s;
  }
  __syncthreads();
  float v = (t < kHW) ? cm[t] : 0.f;
  red[t] = (t < kHW) ? v : 3.4e38f;
  __syncthreads();
  float mn;
  {
    float m = 3.4e38f;
    if (t < 64) {
      for (int i = t; i < 320; i += 64) m = fminf(m, red[i]);
      for (int off = 32; off; off >>= 1) m = fminf(m, __shfl_xor(m, off));
    }
    __syncthreads();
    if (t == 0) red[0] = m;
    __syncthreads();
    mn = red[0];
    __syncthreads();
  }
  red[t] = (t < kHW) ? v : -3.4e38f;
  __syncthreads();
  float mx;
  {
    float m = -3.4e38f;
    if (t < 64) {
      for (int i = t; i < 320; i += 64) m = fmaxf(m, red[i]);
      for (int off = 32; off; off >>= 1) m = fmaxf(m, __shfl_xor(m, off));
    }
    __syncthreads();
    if (t == 0) red[0] = m;
    __syncthreads();
    mx = red[0];
  }
  if (t < kHW) comask[b * kHW + t] = (v - mn) / ((mx - mn) + 1e-12f);
}

// -------- triplet loss --------
__global__ __launch_bounds__(256) void loss_kernel(const float* __restrict__ dap,
                                                   const float* __restrict__ dan,
                                                   const float* __restrict__ comask,
                                                   float* __restrict__ out) {
  int t = threadIdx.x;
  float s = 0.f;
  for (int i = t; i < kB * kHW; i += 256) {
    float da = sqrtf(dap[i]);
    float db = sqrtf(dan[i]);
    float tr = fmaxf(da - db + 0.3f, 0.f);
    s += comask[i] * tr;
  }
  for (int off = 32; off; off >>= 1) s += __shfl_xor(s, off);
  __shared__ float sh[4];
  if ((t & 63) == 0) sh[t >> 6] = s;
  __syncthreads();
  if (t == 0)
    out[(size_t)kB * kC * kHW] = (sh[0] + sh[1] + sh[2] + sh[3]) * (1.f / (float)(kB * kHW));
}

extern "C" void kernel_launch(void* const* d_in, const int* in_sizes, int n_in,
                              void* d_out, int out_size, void* d_ws, size_t ws_size,
                              hipStream_t stream) {
  const float* fv = (const float*)d_in[0];
  const float* ft = (const float*)d_in[1];
  const float* qw = (const float*)d_in[4];
  const float* qb = (const float*)d_in[5];
  const float* kw = (const float*)d_in[6];
  const float* kb = (const float*)d_in[7];
  const int* pos_idx = (const int*)d_in[8];
  const int* neg_idx = (const int*)d_in[9];
  float* out = (float*)d_out;

  constexpr size_t kFQ = (size_t)kB * kCQ * kHW;
  float* ws   = (float*)d_ws;
  float* fq   = ws;
  float* fk   = fq + kFQ;
  unsigned short* wtq = (unsigned short*)(fk + kFQ);
  unsigned short* wtk = wtq + (size_t)9 * kCQ * kC;
  float* pr   = (float*)wtq;                               // alias, live after convs (logits)
  unsigned short* prb = (unsigned short*)(pr + (size_t)kB * kHW * kHW);
  float* maskb   = (float*)(wtk + (size_t)9 * kCQ * kC);
  float* qinv    = maskb + kB * kHW;
  float* kinv    = qinv + kB * kHW;
  float* comaskb = kinv + kB * kHW;
  float* dap     = comaskb + kB * kHW;
  float* dan     = dap + kB * kHW;
  if (ws_size < (size_t)113688576) return;

  zero_kernel<<<dim3((2 * kB * kHW + 255) / 256), 256, 0, stream>>>(dap, 2 * kB * kHW);
  mask_kernel<<<dim3(kB), 320, 0, stream>>>(fv, ft, maskb);
  prep_w_kernel<<<dim3(kCQ, 2), 256, 0, stream>>>(qw, kw, wtq, wtk);
  conv_fused_kernel<<<dim3(256), 512, 0, stream>>>(wtq, wtk, qb, kb, fv, ft, fq, fk);
  norminv_kernel<<<dim3(kB, 2), 320, 0, stream>>>(fq, fk, qinv, kinv);

  // positive branch (pr/prb overwrite wt region — weights dead now)
  sim_kernel<<<dim3(9, kB), 320, 0, stream>>>(fq, fk, qinv, kinv, pos_idx, pr);
  softmax_kernel<<<dim3(kB * kHW), 320, 0, stream>>>(pr, prb);
  comask_kernel<<<dim3(kB), 320, 0, stream>>>(prb, maskb, pos_idx, comaskb);
  warp_mfma_kernel<<<dim3(16, kB), 512, 0, stream>>>(fv, ft, prb, maskb, pos_idx, out, dap, 1);

  // negative branch
  sim_kernel<<<dim3(9, kB), 320, 0, stream>>>(fq, fk, qinv, kinv, neg_idx, pr);
  softmax_kernel<<<dim3(kB * kHW), 320, 0, stream>>>(pr, prb);
  warp_mfma_kernel<<<dim3(16, kB), 512, 0, stream>>>(fv, ft, prb, maskb, neg_idx, out, dan, 0);

  loss_kernel<<<dim3(1), 256, 0, stream>>>(dap, dan, comaskb, out);
}

// Round 13
// 1599.166 us; speedup vs baseline: 1.8156x; 1.8156x over previous
//
#include <hip/hip_runtime.h>
#include <cstdint>
#include <cstddef>

// CMAlign forward. R13: R11 conv (best measured, 628us) restored exactly.
// New: mask computed in 2 passes (256-block partial sums + 64-block finalize)
// to fix its 64-block under-parallelism. Partial buffer aliases wtq (dead until prep_w).
// Shapes: B=64, C=2048, Cq=512, H=24, W=12, HW=288.

namespace {
constexpr int kB    = 64;
constexpr int kHalf = 32;
constexpr int kC    = 2048;
constexpr int kCQ   = 512;
constexpr int kH    = 24;
constexpr int kW    = 12;
constexpr int kHW   = 288;
constexpr float kTemp = 50.0f;
constexpr int kXPlane = 366;  // 16B cells; 5856 B = 96 mod 128 -> kg quadrant offsets
}

typedef __attribute__((ext_vector_type(8))) __bf16 bf16x8;
typedef __attribute__((ext_vector_type(4))) float f32x4;
typedef __attribute__((ext_vector_type(8))) unsigned short ushort8;

__device__ __forceinline__ const float* feat_base(const float* fv, const float* ft, int b) {
  return (b < kHalf) ? (fv + (size_t)b * kC * kHW)
                     : (ft + (size_t)(b - kHalf) * kC * kHW);
}

__device__ __forceinline__ unsigned short f2bf(float f) {
  union { float f; unsigned u; } c; c.f = f;
  unsigned u = c.u;
  unsigned r = (u + 0x7FFFu + ((u >> 16) & 1u)) >> 16;  // RNE
  return (unsigned short)r;
}

__device__ __forceinline__ float bf2f(unsigned short h) {
  union { unsigned u; float f; } c; c.u = ((unsigned)h) << 16;
  return c.f;
}

__device__ __forceinline__ void gload_lds16(const void* g, void* l) {
  __builtin_amdgcn_global_load_lds(
      (const __attribute__((address_space(1))) unsigned int*)g,
      (__attribute__((address_space(3))) unsigned int*)l, 16, 0, 0);
}

__global__ void zero_kernel(float* __restrict__ p, int n) {
  int i = blockIdx.x * 256 + threadIdx.x;
  if (i < n) p[i] = 0.f;
}

// -------- weight prep: w[oc][ic][3][3] fp32 -> MFMA-image wt2 --------
// wt2[chunk64][tap9][fragG32][lane64][j8]; lane = (oc&15) + kg*16, kg=(ic>>3)&3, j=ic&7.
__global__ __launch_bounds__(256) void prep_w_kernel(const float* __restrict__ qw,
                                                     const float* __restrict__ kw,
                                                     unsigned short* __restrict__ wtq,
                                                     unsigned short* __restrict__ wtk) {
  int oc = blockIdx.x;
  int z  = blockIdx.y;
  const float* w = (z ? kw : qw) + (size_t)oc * (kC * 9);
  unsigned short* wt = z ? wtk : wtq;
  __shared__ unsigned short lw[kC * 9];  // [ic][tap]
  int t = threadIdx.x;
#pragma unroll
  for (int it = 0; it < 18; ++it) {
    int i4 = (it * 256 + t) * 4;
    float4 v = *(const float4*)(w + i4);
    lw[i4 + 0] = f2bf(v.x);
    lw[i4 + 1] = f2bf(v.y);
    lw[i4 + 2] = f2bf(v.z);
    lw[i4 + 3] = f2bf(v.w);
  }
  __syncthreads();
  for (int item = t; item < 9 * 256; item += 256) {
    int tap = item >> 8;
    int icb = item & 255;  // ic octet index; ic = icb*8
    ushort8 pk;
#pragma unroll
    for (int j = 0; j < 8; ++j) pk[j] = lw[(icb * 8 + j) * 9 + tap];
    size_t dst16 = (((size_t)(icb >> 2) * 9 + tap) * 32 + (oc >> 4)) * 64
                   + (oc & 15) + (icb & 3) * 16;
    *(ushort8*)(wt + dst16 * 8) = pk;
  }
}

// -------- FUSED MFMA conv: q+k convs, tile M=128(oc) x N=288(pos), K=2048x9 --------
// Shared Xs; Wbuf[2 buf][3 tap][2 conv][8KB] double-buffered per 3-tap group.
// X staged with TRANSIENT regs at chunk top; halo cells zeroed once. (R7/R11 structure.)
__global__ __launch_bounds__(512, 1) void conv_fused_kernel(const unsigned short* __restrict__ wtq,
                                                            const unsigned short* __restrict__ wtk,
                                                            const float* __restrict__ qb,
                                                            const float* __restrict__ kb,
                                                            const float* __restrict__ fv,
                                                            const float* __restrict__ ft,
                                                            float* __restrict__ fqo,
                                                            float* __restrict__ fko) {
  __shared__ unsigned short Wbuf[2 * 6 * 4096];   // [buf][slot r*2+cv][frag8][lane64][j8] 98304 B
  __shared__ unsigned short Xs[4 * kXPlane * 8];  // [kg][hp 366][8ic] 23424 B
  int t    = threadIdx.x;
  int lane = t & 63;
  int wid  = t >> 6;
  int l15  = lane & 15, kg = lane >> 4;
  int wm   = wid & 1, wn = wid >> 1;  // 2M x 4N
  // XCD-clustered decode
  int n    = blockIdx.x;
  int xcd  = n & 7;
  int oc0  = (xcd >> 1) * 128;
  int b    = ((xcd & 1) << 5) + (n >> 3);
  int f0   = oc0 >> 4;  // global frag base
  const float* fb = feat_base(fv, ft, b);
  const char* wtqB = (const char*)wtq;
  const char* wtkB = (const char*)wtk;

  // Xs staging descriptors: item = i*512 + t; item = xkg*366 + hp
  int  xoff[3];
  bool xvalid[3], xhas[3];
#pragma unroll
  for (int i = 0; i < 3; ++i) {
    int item = i * 512 + t;
    xhas[i] = item < 4 * kXPlane;
    int xkg = item / kXPlane;
    int hp  = item - xkg * kXPlane;
    int hy = hp / 14, hx = hp - hy * 14;
    int y = hy - 1, x = hx - 1;
    bool v = xhas[i] && hp < 364 && (y >= 0 && y < kH && x >= 0 && x < kW);
    xvalid[i] = v;
    xoff[i] = v ? (xkg * 8) * kHW + y * kW + x : 0;
  }

  // A-frag read byte addrs within an 8KB slot: lane-linear, conflict-free
  int aAddr[4];
#pragma unroll
  for (int fm = 0; fm < 4; ++fm)
    aAddr[fm] = (((wm * 4 + fm) * 64) + lane) * 16;
  // B-frag read byte addrs
  int nfn = (wn < 2) ? 5 : 4;
  int fnb = (wn < 2) ? wn * 5 : 10 + (wn - 2) * 4;
  int bAddr[5];
#pragma unroll
  for (int fi = 0; fi < 5; ++fi) {
    int p = (fnb + fi) * 16 + l15;
    if (p > 287) p = 287;  // only for unused frags
    int y = p / kW, x = p - y * kW;
    bAddr[fi] = kg * (kXPlane * 16) + ((y + 1) * 14 + (x + 1)) * 16;  // + d16 per tap
  }

  f32x4 acc[2][4][5];
#pragma unroll
  for (int cv = 0; cv < 2; ++cv)
#pragma unroll
    for (int fm = 0; fm < 4; ++fm)
#pragma unroll
      for (int fi = 0; fi < 5; ++fi) acc[cv][fm][fi] = (f32x4){0.f, 0.f, 0.f, 0.f};

  char* WsB = (char*)Wbuf;
  char* XsB = (char*)Xs;
  int wavebase = t & ~63;

  // prologue: zero halo/pad X cells ONCE (never rewritten); stage group (0,0) -> buf0
#pragma unroll
  for (int i = 0; i < 3; ++i) {
    if (xhas[i] && !xvalid[i]) {
      ushort8 pk;
#pragma unroll
      for (int j = 0; j < 8; ++j) pk[j] = 0;
      *(ushort8*)(XsB + (size_t)(i * 512 + t) * 16) = pk;
    }
  }
#pragma unroll
  for (int r = 0; r < 3; ++r) {
    size_t g16 = ((size_t)r * 32 + f0 + wid) * 64 + lane;
    gload_lds16(wtqB + g16 * 16, WsB + (size_t)(r * 2 + 0) * 8192 + wavebase * 16);
    gload_lds16(wtkB + g16 * 16, WsB + (size_t)(r * 2 + 1) * 8192 + wavebase * 16);
  }

  int buf = 0;
#pragma unroll 1
  for (int chunk = 0; chunk < 64; ++chunk) {
    int ic0 = chunk * 32;
    // X: load (transient regs) -> cvt -> LDS, valid cells only
    {
      float xv[3][8];
#pragma unroll
      for (int i = 0; i < 3; ++i)
        if (xvalid[i]) {
          const float* s = fb + (size_t)ic0 * kHW + xoff[i];
#pragma unroll
          for (int j = 0; j < 8; ++j) xv[i][j] = s[(size_t)j * kHW];
        }
#pragma unroll
      for (int i = 0; i < 3; ++i) {
        if (!xvalid[i]) continue;
        ushort8 pk;
#pragma unroll
        for (int j = 0; j < 8; ++j) pk[j] = f2bf(xv[i][j]);
        *(ushort8*)(XsB + (size_t)(i * 512 + t) * 16) = pk;
      }
    }
    __syncthreads();  // X visible + prior W staging drained

#pragma unroll 1
    for (int g = 0; g < 3; ++g) {
      // stage next 3-tap group into the other buffer
      bool hn = (g < 2) || (chunk < 63);
      if (hn) {
        int nchunk = (g < 2) ? chunk : chunk + 1;
        int ng     = (g < 2) ? g + 1 : 0;
#pragma unroll
        for (int r = 0; r < 3; ++r) {
          size_t g16 = ((size_t)(nchunk * 9 + ng * 3 + r) * 32 + f0 + wid) * 64 + lane;
          gload_lds16(wtqB + g16 * 16,
                      WsB + (size_t)((buf ^ 1) * 6 + r * 2 + 0) * 8192 + wavebase * 16);
          gload_lds16(wtkB + g16 * 16,
                      WsB + (size_t)((buf ^ 1) * 6 + r * 2 + 1) * 8192 + wavebase * 16);
        }
      }
      // compute current group: 3 taps x 2 convs x 4 fm x nfn
#pragma unroll
      for (int r = 0; r < 3; ++r) {
        int tap = g * 3 + r;
        int d16 = ((tap / 3 - 1) * 14 + (tap % 3 - 1)) * 16;
        bf16x8 af[2][4];
#pragma unroll
        for (int cv = 0; cv < 2; ++cv)
#pragma unroll
          for (int fm = 0; fm < 4; ++fm)
            af[cv][fm] = *(const bf16x8*)(WsB + (size_t)(buf * 6 + r * 2 + cv) * 8192 + aAddr[fm]);
#pragma unroll
        for (int fi = 0; fi < 5; ++fi) {
          if (fi >= nfn) continue;  // wave-uniform
          bf16x8 bb = *(const bf16x8*)(XsB + bAddr[fi] + d16);
#pragma unroll
          for (int cv = 0; cv < 2; ++cv)
#pragma unroll
            for (int fm = 0; fm < 4; ++fm)
              acc[cv][fm][fi] =
                  __builtin_amdgcn_mfma_f32_16x16x32_bf16(af[cv][fm], bb, acc[cv][fm][fi], 0, 0, 0);
        }
      }
      __syncthreads();  // all waves done with buf; next staging drained at next barrier
      buf ^= 1;
    }
  }

  // epilogue: C row(oc) = kg*4+reg (+fm*16+wm*64), col(p) = l15 (+frag base)
#pragma unroll
  for (int cv = 0; cv < 2; ++cv) {
    float* outp = cv ? fko : fqo;
    const float* bias = cv ? kb : qb;
#pragma unroll
    for (int fi = 0; fi < 5; ++fi) {
      if (fi >= nfn) continue;
      int p = (fnb + fi) * 16 + l15;
#pragma unroll
      for (int fm = 0; fm < 4; ++fm)
#pragma unroll
        for (int reg = 0; reg < 4; ++reg) {
          int oc = oc0 + wm * 64 + fm * 16 + kg * 4 + reg;
          outp[((size_t)b * kCQ + oc) * kHW + p] = acc[cv][fm][fi][reg] + bias[oc];
        }
    }
  }
}

// -------- warp GEMM via MFMA: W[c,q] = sum_k tgt[c,k]*pr[q,k] + recon + dist^2 --------
__global__ __launch_bounds__(512) void warp_mfma_kernel(const float* __restrict__ fv,
                                                        const float* __restrict__ ft,
                                                        const unsigned short* __restrict__ prb,
                                                        const float* __restrict__ maskp,
                                                        const int* __restrict__ idx,
                                                        float* __restrict__ outp,
                                                        float* __restrict__ dsq,
                                                        int write_out) {
  __shared__ unsigned short AsHi[128 * 32];
  __shared__ unsigned short AsLo[128 * 32];
  __shared__ unsigned short Bs[288 * 32];
  int t    = threadIdx.x;
  int lane = t & 63;
  int wid  = t >> 6;
  int l15  = lane & 15, kg = lane >> 4;
  int wm   = wid >> 1, wn = wid & 1;
  int c0   = blockIdx.x * 128;
  int b    = blockIdx.y;
  int tb   = idx[b];
  const float* tgt = feat_base(fv, ft, tb);
  const float* fb  = feat_base(fv, ft, b);

  int ar = t >> 2, as = t & 3;
  int aslot = as ^ ((ar ^ (ar >> 2)) & 3);
  unsigned short* aDstHi = AsHi + ar * 32 + aslot * 8;
  unsigned short* aDstLo = AsLo + ar * 32 + aslot * 8;

  int aIdx[2];
#pragma unroll
  for (int fm = 0; fm < 2; ++fm) {
    int r = wm * 32 + fm * 16 + l15;
    aIdx[fm] = r * 32 + (kg ^ ((r ^ (r >> 2)) & 3)) * 8;
  }
  int bIdx[9];
#pragma unroll
  for (int fn = 0; fn < 9; ++fn) {
    int q = wn * 144 + fn * 16 + l15;
    bIdx[fn] = q * 32 + (kg ^ ((q ^ (q >> 2)) & 3)) * 8;
  }

  f32x4 acc[2][9];
#pragma unroll
  for (int fm = 0; fm < 2; ++fm)
#pragma unroll
    for (int fn = 0; fn < 9; ++fn) acc[fm][fn] = (f32x4){0.f, 0.f, 0.f, 0.f};

#pragma unroll 1
  for (int chunk = 0; chunk < 9; ++chunk) {
    int k0 = chunk * 32;
    __syncthreads();
    {
      const float* s = tgt + (size_t)(c0 + ar) * kHW + k0 + as * 8;
      float4 v0 = *(const float4*)(s);
      float4 v1 = *(const float4*)(s + 4);
      float xs[8] = {v0.x, v0.y, v0.z, v0.w, v1.x, v1.y, v1.z, v1.w};
      ushort8 hi, lo;
#pragma unroll
      for (int j = 0; j < 8; ++j) {
        unsigned short h = f2bf(xs[j]);
        hi[j] = h;
        lo[j] = f2bf(xs[j] - bf2f(h));
      }
      *(ushort8*)aDstHi = hi;
      *(ushort8*)aDstLo = lo;
    }
#pragma unroll
    for (int i = 0; i < 3; ++i) {
      int item = i * 512 + t;
      if (item < 1152) {
        int q = item >> 2, s = item & 3;
        ushort8 v = *(const ushort8*)(prb + ((size_t)b * kHW + q) * kHW + k0 + s * 8);
        *(ushort8*)(Bs + q * 32 + (s ^ ((q ^ (q >> 2)) & 3)) * 8) = v;
      }
    }
    __syncthreads();
    bf16x8 ah0 = *(const bf16x8*)(AsHi + aIdx[0]);
    bf16x8 al0 = *(const bf16x8*)(AsLo + aIdx[0]);
    bf16x8 ah1 = *(const bf16x8*)(AsHi + aIdx[1]);
    bf16x8 al1 = *(const bf16x8*)(AsLo + aIdx[1]);
#pragma unroll
    for (int fn = 0; fn < 9; ++fn) {
      bf16x8 bb = *(const bf16x8*)(Bs + bIdx[fn]);
      acc[0][fn] = __builtin_amdgcn_mfma_f32_16x16x32_bf16(ah0, bb, acc[0][fn], 0, 0, 0);
      acc[0][fn] = __builtin_amdgcn_mfma_f32_16x16x32_bf16(al0, bb, acc[0][fn], 0, 0, 0);
      acc[1][fn] = __builtin_amdgcn_mfma_f32_16x16x32_bf16(ah1, bb, acc[1][fn], 0, 0, 0);
      acc[1][fn] = __builtin_amdgcn_mfma_f32_16x16x32_bf16(al1, bb, acc[1][fn], 0, 0, 0);
    }
  }

#pragma unroll
  for (int fn = 0; fn < 9; ++fn) {
    int q = wn * 144 + fn * 16 + l15;
    float mj = maskp[b * kHW + q];
    float psum = 0.f;
#pragma unroll
    for (int fm = 0; fm < 2; ++fm) {
#pragma unroll
      for (int reg = 0; reg < 4; ++reg) {
        int c = c0 + wm * 32 + fm * 16 + kg * 4 + reg;
        float fvv = fb[(size_t)c * kHW + q];
        float Wv  = acc[fm][fn][reg];
        float d   = mj * (fvv - Wv) + 1e-6f;
        psum      = fmaf(d, d, psum);
        if (write_out)
          outp[((size_t)b * kC + c) * kHW + q] = mj * Wv + (1.f - mj) * fvv;
      }
    }
    psum += __shfl_xor(psum, 16);
    psum += __shfl_xor(psum, 32);
    if (lane < 16) atomicAdd(&dsq[b * kHW + q], psum);
  }
}

// -------- mask pass 1: partial channel sum-of-squares over 512-c slices --------
__global__ __launch_bounds__(320) void mask_part_kernel(const float* __restrict__ fv,
                                                        const float* __restrict__ ft,
                                                        float* __restrict__ part) {
  int b = blockIdx.x;
  int s = blockIdx.y;
  int t = threadIdx.x;
  if (t >= kHW) return;
  const float* fb = feat_base(fv, ft, b) + (size_t)(s * 512) * kHW;
  float sum = 0.f;
  for (int c = 0; c < 512; ++c) { float v = fb[(size_t)c * kHW + t]; sum += v * v; }
  part[((size_t)b * 4 + s) * kHW + t] = sum;
}

// -------- mask pass 2: finalize sqrt + per-sample min-max normalize --------
__global__ __launch_bounds__(320) void mask_fin_kernel(const float* __restrict__ part,
                                                       float* __restrict__ mask) {
  int b = blockIdx.x;
  int t = threadIdx.x;
  float n = 0.f;
  if (t < kHW) {
    const float* pb = part + (size_t)b * 4 * kHW;
    n = sqrtf(pb[t] + pb[kHW + t] + pb[2 * kHW + t] + pb[3 * kHW + t]);
  }
  __shared__ float sh[320];
  sh[t] = (t < kHW) ? n : 3.4e38f;
  __syncthreads();
  float mn;
  {
    float m = 3.4e38f;
    if (t < 64) {
      for (int i = t; i < 320; i += 64) m = fminf(m, sh[i]);
      for (int off = 32; off; off >>= 1) m = fminf(m, __shfl_xor(m, off));
    }
    __syncthreads();
    if (t == 0) sh[0] = m;
    __syncthreads();
    mn = sh[0];
    __syncthreads();
  }
  sh[t] = (t < kHW) ? n : -3.4e38f;
  __syncthreads();
  float mx;
  {
    float m = -3.4e38f;
    if (t < 64) {
      for (int i = t; i < 320; i += 64) m = fmaxf(m, sh[i]);
      for (int off = 32; off; off >>= 1) m = fmaxf(m, __shfl_xor(m, off));
    }
    __syncthreads();
    if (t == 0) sh[0] = m;
    __syncthreads();
    mx = sh[0];
  }
  if (t < kHW) mask[b * kHW + t] = (n - mn) / ((mx - mn) + 1e-12f);
}

// -------- per-(b,pos) inverse L2 norm over projected channels --------
__global__ __launch_bounds__(320) void norminv_kernel(const float* __restrict__ fq,
                                                      const float* __restrict__ fk,
                                                      float* __restrict__ qinv,
                                                      float* __restrict__ kinv) {
  int b = blockIdx.x;
  int z = blockIdx.y;
  const float* src = z ? fk : fq;
  float* dst       = z ? kinv : qinv;
  int t = threadIdx.x;
  if (t >= kHW) return;
  const float* sb = src + (size_t)b * kCQ * kHW;
  float s = 0.f;
  for (int c = 0; c < kCQ; ++c) { float v = sb[(size_t)c * kHW + t]; s += v * v; }
  float n = sqrtf(s);
  dst[b * kHW + t] = 1.f / fmaxf(n, 1e-12f);
}

// -------- sim logits --------
__global__ __launch_bounds__(320) void sim_kernel(const float* __restrict__ fq,
                                                  const float* __restrict__ fk,
                                                  const float* __restrict__ qinv,
                                                  const float* __restrict__ kinv,
                                                  const int* __restrict__ idx,
                                                  float* __restrict__ logits) {
  int b  = blockIdx.y;
  int q0 = blockIdx.x * 32;
  int t  = threadIdx.x;
  if (t >= kHW) return;
  int tb = idx[b];
  const float* fqb = fq + (size_t)b * kCQ * kHW + q0;
  const float* fkb = fk + (size_t)tb * kCQ * kHW;
  float acc[32];
#pragma unroll
  for (int q = 0; q < 32; ++q) acc[q] = 0.f;
#pragma unroll 1
  for (int c = 0; c < kCQ; ++c) {
    float kv = fkb[(size_t)c * kHW + t];
#pragma unroll
    for (int q = 0; q < 32; ++q) acc[q] = fmaf(fqb[(size_t)c * kHW + q], kv, acc[q]);
  }
  float ks = kinv[tb * kHW + t];
#pragma unroll
  for (int q = 0; q < 32; ++q) {
    float lg = kTemp * qinv[b * kHW + q0 + q] * ks * acc[q];
    logits[((size_t)b * kHW + q0 + q) * kHW + t] = lg;
  }
}

// -------- row softmax over k; emits bf16 only --------
__global__ __launch_bounds__(320) void softmax_kernel(const float* __restrict__ pr,
                                                      unsigned short* __restrict__ prb) {
  int row = blockIdx.x;
  int t   = threadIdx.x;
  const float* rp = pr + (size_t)row * kHW;
  float v = (t < kHW) ? rp[t] : -3.4e38f;
  __shared__ float sh[5];
  int wv = t >> 6, l = t & 63;
  float m = v;
  for (int off = 32; off; off >>= 1) m = fmaxf(m, __shfl_xor(m, off));
  if (l == 0) sh[wv] = m;
  __syncthreads();
  if (t == 0) { float mm = sh[0]; for (int i = 1; i < 5; ++i) mm = fmaxf(mm, sh[i]); sh[0] = mm; }
  __syncthreads();
  m = sh[0];
  float e = (t < kHW) ? __expf(v - m) : 0.f;
  float s = e;
  for (int off = 32; off; off >>= 1) s += __shfl_xor(s, off);
  __syncthreads();
  if (l == 0) sh[wv] = s;
  __syncthreads();
  if (t == 0) { float ss = sh[0]; for (int i = 1; i < 5; ++i) ss += sh[i]; sh[0] = ss; }
  __syncthreads();
  s = sh[0];
  if (t < kHW) prb[(size_t)row * kHW + t] = f2bf(e / s);
}

// -------- comask (reads bf16 pr) --------
__global__ __launch_bounds__(320) void comask_kernel(const unsigned short* __restrict__ prb,
                                                     const float* __restrict__ mask,
                                                     const int* __restrict__ idx,
                                                     float* __restrict__ comask) {
  int b = blockIdx.x;
  int t = threadIdx.x;
  int tb = idx[b];
  __shared__ float mt[kHW];
  __shared__ float cm[kHW];
  __shared__ float red[320];
  if (t < kHW) mt[t] = mask[tb * kHW + t];
  __syncthreads();
  int wv = t >> 6, l = t & 63;
  for (int q = wv; q < kHW; q += 5) {
    const unsigned short* prow = prb + ((size_t)b * kHW + q) * kHW;
    float s = 0.f;
    for (int k = l; k < kHW; k += 64) s += bf2f(prow[k]) * mt[k];
    for (int off = 32; off; off >>= 1) s += __shfl_xor(s, off);
    if (l == 0) cm[q] = mask[b * kHW + q] * s;
  }
  __syncthreads();
  float v = (t < kHW) ? cm[t] : 0.f;
  red[t] = (t < kHW) ? v : 3.4e38f;
  __syncthreads();
  float mn;
  {
    float m = 3.4e38f;
    if (t < 64) {
      for (int i = t; i < 320; i += 64) m = fminf(m, red[i]);
      for (int off = 32; off; off >>= 1) m = fminf(m, __shfl_xor(m, off));
    }
    __syncthreads();
    if (t == 0) red[0] = m;
    __syncthreads();
    mn = red[0];
    __syncthreads();
  }
  red[t] = (t < kHW) ? v : -3.4e38f;
  __syncthreads();
  float mx;
  {
    float m = -3.4e38f;
    if (t < 64) {
      for (int i = t; i < 320; i += 64) m = fmaxf(m, red[i]);
      for (int off = 32; off; off >>= 1) m = fmaxf(m, __shfl_xor(m, off));
    }
    __syncthreads();
    if (t == 0) red[0] = m;
    __syncthreads();
    mx = red[0];
  }
  if (t < kHW) comask[b * kHW + t] = (v - mn) / ((mx - mn) + 1e-12f);
}

// -------- triplet loss --------
__global__ __launch_bounds__(256) void loss_kernel(const float* __restrict__ dap,
                                                   const float* __restrict__ dan,
                                                   const float* __restrict__ comask,
                                                   float* __restrict__ out) {
  int t = threadIdx.x;
  float s = 0.f;
  for (int i = t; i < kB * kHW; i += 256) {
    float da = sqrtf(dap[i]);
    float db = sqrtf(dan[i]);
    float tr = fmaxf(da - db + 0.3f, 0.f);
    s += comask[i] * tr;
  }
  for (int off = 32; off; off >>= 1) s += __shfl_xor(s, off);
  __shared__ float sh[4];
  if ((t & 63) == 0) sh[t >> 6] = s;
  __syncthreads();
  if (t == 0)
    out[(size_t)kB * kC * kHW] = (sh[0] + sh[1] + sh[2] + sh[3]) * (1.f / (float)(kB * kHW));
}

extern "C" void kernel_launch(void* const* d_in, const int* in_sizes, int n_in,
                              void* d_out, int out_size, void* d_ws, size_t ws_size,
                              hipStream_t stream) {
  const float* fv = (const float*)d_in[0];
  const float* ft = (const float*)d_in[1];
  const float* qw = (const float*)d_in[4];
  const float* qb = (const float*)d_in[5];
  const float* kw = (const float*)d_in[6];
  const float* kb = (const float*)d_in[7];
  const int* pos_idx = (const int*)d_in[8];
  const int* neg_idx = (const int*)d_in[9];
  float* out = (float*)d_out;

  constexpr size_t kFQ = (size_t)kB * kCQ * kHW;
  float* ws   = (float*)d_ws;
  float* fq   = ws;
  float* fk   = fq + kFQ;
  unsigned short* wtq = (unsigned short*)(fk + kFQ);
  unsigned short* wtk = wtq + (size_t)9 * kCQ * kC;
  float* pr   = (float*)wtq;                               // alias, live after convs (logits)
  unsigned short* prb = (unsigned short*)(pr + (size_t)kB * kHW * kHW);
  float* part = (float*)wtq;                               // alias: mask partials, dead before prep_w
  float* maskb   = (float*)(wtk + (size_t)9 * kCQ * kC);
  float* qinv    = maskb + kB * kHW;
  float* kinv    = qinv + kB * kHW;
  float* comaskb = kinv + kB * kHW;
  float* dap     = comaskb + kB * kHW;
  float* dan     = dap + kB * kHW;
  if (ws_size < (size_t)113688576) return;

  zero_kernel<<<dim3((2 * kB * kHW + 255) / 256), 256, 0, stream>>>(dap, 2 * kB * kHW);
  mask_part_kernel<<<dim3(kB, 4), 320, 0, stream>>>(fv, ft, part);
  mask_fin_kernel<<<dim3(kB), 320, 0, stream>>>(part, maskb);
  prep_w_kernel<<<dim3(kCQ, 2), 256, 0, stream>>>(qw, kw, wtq, wtk);
  conv_fused_kernel<<<dim3(256), 512, 0, stream>>>(wtq, wtk, qb, kb, fv, ft, fq, fk);
  norminv_kernel<<<dim3(kB, 2), 320, 0, stream>>>(fq, fk, qinv, kinv);

  // positive branch (pr/prb overwrite wt region — weights dead now)
  sim_kernel<<<dim3(9, kB), 320, 0, stream>>>(fq, fk, qinv, kinv, pos_idx, pr);
  softmax_kernel<<<dim3(kB * kHW), 320, 0, stream>>>(pr, prb);
  comask_kernel<<<dim3(kB), 320, 0, stream>>>(prb, maskb, pos_idx, comaskb);
  warp_mfma_kernel<<<dim3(16, kB), 512, 0, stream>>>(fv, ft, prb, maskb, pos_idx, out, dap, 1);

  // negative branch
  sim_kernel<<<dim3(9, kB), 320, 0, stream>>>(fq, fk, qinv, kinv, neg_idx, pr);
  softmax_kernel<<<dim3(kB * kHW), 320, 0, stream>>>(pr, prb);
  warp_mfma_kernel<<<dim3(16, kB), 512, 0, stream>>>(fv, ft, prb, maskb, neg_idx, out, dan, 0);

  loss_kernel<<<dim3(1), 256, 0, stream>>>(dap, dan, comaskb, out);
}

// Round 14
// 1531.942 us; speedup vs baseline: 1.8952x; 1.0439x over previous
//
#include <hip/hip_runtime.h>
#include <cstdint>
#include <cstddef>

// CMAlign forward. R14: R13 + sim/softmax FUSION — sim block already holds full
// 288-k rows (one elem/thread); softmax done in-block via LDS transpose, bf16 P
// written directly. Removes 2 launches + 85MB of pr fp32 round-trip.
// Conv untouched (R11 best, 628us). Shapes: B=64, C=2048, Cq=512, H=24, W=12, HW=288.

namespace {
constexpr int kB    = 64;
constexpr int kHalf = 32;
constexpr int kC    = 2048;
constexpr int kCQ   = 512;
constexpr int kH    = 24;
constexpr int kW    = 12;
constexpr int kHW   = 288;
constexpr float kTemp = 50.0f;
constexpr int kXPlane = 366;  // 16B cells; 5856 B = 96 mod 128 -> kg quadrant offsets
}

typedef __attribute__((ext_vector_type(8))) __bf16 bf16x8;
typedef __attribute__((ext_vector_type(4))) float f32x4;
typedef __attribute__((ext_vector_type(8))) unsigned short ushort8;

__device__ __forceinline__ const float* feat_base(const float* fv, const float* ft, int b) {
  return (b < kHalf) ? (fv + (size_t)b * kC * kHW)
                     : (ft + (size_t)(b - kHalf) * kC * kHW);
}

__device__ __forceinline__ unsigned short f2bf(float f) {
  union { float f; unsigned u; } c; c.f = f;
  unsigned u = c.u;
  unsigned r = (u + 0x7FFFu + ((u >> 16) & 1u)) >> 16;  // RNE
  return (unsigned short)r;
}

__device__ __forceinline__ float bf2f(unsigned short h) {
  union { unsigned u; float f; } c; c.u = ((unsigned)h) << 16;
  return c.f;
}

__device__ __forceinline__ void gload_lds16(const void* g, void* l) {
  __builtin_amdgcn_global_load_lds(
      (const __attribute__((address_space(1))) unsigned int*)g,
      (__attribute__((address_space(3))) unsigned int*)l, 16, 0, 0);
}

__global__ void zero_kernel(float* __restrict__ p, int n) {
  int i = blockIdx.x * 256 + threadIdx.x;
  if (i < n) p[i] = 0.f;
}

// -------- weight prep: w[oc][ic][3][3] fp32 -> MFMA-image wt2 --------
// wt2[chunk64][tap9][fragG32][lane64][j8]; lane = (oc&15) + kg*16, kg=(ic>>3)&3, j=ic&7.
__global__ __launch_bounds__(256) void prep_w_kernel(const float* __restrict__ qw,
                                                     const float* __restrict__ kw,
                                                     unsigned short* __restrict__ wtq,
                                                     unsigned short* __restrict__ wtk) {
  int oc = blockIdx.x;
  int z  = blockIdx.y;
  const float* w = (z ? kw : qw) + (size_t)oc * (kC * 9);
  unsigned short* wt = z ? wtk : wtq;
  __shared__ unsigned short lw[kC * 9];  // [ic][tap]
  int t = threadIdx.x;
#pragma unroll
  for (int it = 0; it < 18; ++it) {
    int i4 = (it * 256 + t) * 4;
    float4 v = *(const float4*)(w + i4);
    lw[i4 + 0] = f2bf(v.x);
    lw[i4 + 1] = f2bf(v.y);
    lw[i4 + 2] = f2bf(v.z);
    lw[i4 + 3] = f2bf(v.w);
  }
  __syncthreads();
  for (int item = t; item < 9 * 256; item += 256) {
    int tap = item >> 8;
    int icb = item & 255;  // ic octet index; ic = icb*8
    ushort8 pk;
#pragma unroll
    for (int j = 0; j < 8; ++j) pk[j] = lw[(icb * 8 + j) * 9 + tap];
    size_t dst16 = (((size_t)(icb >> 2) * 9 + tap) * 32 + (oc >> 4)) * 64
                   + (oc & 15) + (icb & 3) * 16;
    *(ushort8*)(wt + dst16 * 8) = pk;
  }
}

// -------- FUSED MFMA conv: q+k convs, tile M=128(oc) x N=288(pos), K=2048x9 --------
// Shared Xs; Wbuf[2 buf][3 tap][2 conv][8KB] double-buffered per 3-tap group.
// X staged with TRANSIENT regs at chunk top; halo cells zeroed once. (R7/R11 structure.)
__global__ __launch_bounds__(512, 1) void conv_fused_kernel(const unsigned short* __restrict__ wtq,
                                                            const unsigned short* __restrict__ wtk,
                                                            const float* __restrict__ qb,
                                                            const float* __restrict__ kb,
                                                            const float* __restrict__ fv,
                                                            const float* __restrict__ ft,
                                                            float* __restrict__ fqo,
                                                            float* __restrict__ fko) {
  __shared__ unsigned short Wbuf[2 * 6 * 4096];   // [buf][slot r*2+cv][frag8][lane64][j8] 98304 B
  __shared__ unsigned short Xs[4 * kXPlane * 8];  // [kg][hp 366][8ic] 23424 B
  int t    = threadIdx.x;
  int lane = t & 63;
  int wid  = t >> 6;
  int l15  = lane & 15, kg = lane >> 4;
  int wm   = wid & 1, wn = wid >> 1;  // 2M x 4N
  // XCD-clustered decode
  int n    = blockIdx.x;
  int xcd  = n & 7;
  int oc0  = (xcd >> 1) * 128;
  int b    = ((xcd & 1) << 5) + (n >> 3);
  int f0   = oc0 >> 4;  // global frag base
  const float* fb = feat_base(fv, ft, b);
  const char* wtqB = (const char*)wtq;
  const char* wtkB = (const char*)wtk;

  // Xs staging descriptors: item = i*512 + t; item = xkg*366 + hp
  int  xoff[3];
  bool xvalid[3], xhas[3];
#pragma unroll
  for (int i = 0; i < 3; ++i) {
    int item = i * 512 + t;
    xhas[i] = item < 4 * kXPlane;
    int xkg = item / kXPlane;
    int hp  = item - xkg * kXPlane;
    int hy = hp / 14, hx = hp - hy * 14;
    int y = hy - 1, x = hx - 1;
    bool v = xhas[i] && hp < 364 && (y >= 0 && y < kH && x >= 0 && x < kW);
    xvalid[i] = v;
    xoff[i] = v ? (xkg * 8) * kHW + y * kW + x : 0;
  }

  // A-frag read byte addrs within an 8KB slot: lane-linear, conflict-free
  int aAddr[4];
#pragma unroll
  for (int fm = 0; fm < 4; ++fm)
    aAddr[fm] = (((wm * 4 + fm) * 64) + lane) * 16;
  // B-frag read byte addrs
  int nfn = (wn < 2) ? 5 : 4;
  int fnb = (wn < 2) ? wn * 5 : 10 + (wn - 2) * 4;
  int bAddr[5];
#pragma unroll
  for (int fi = 0; fi < 5; ++fi) {
    int p = (fnb + fi) * 16 + l15;
    if (p > 287) p = 287;  // only for unused frags
    int y = p / kW, x = p - y * kW;
    bAddr[fi] = kg * (kXPlane * 16) + ((y + 1) * 14 + (x + 1)) * 16;  // + d16 per tap
  }

  f32x4 acc[2][4][5];
#pragma unroll
  for (int cv = 0; cv < 2; ++cv)
#pragma unroll
    for (int fm = 0; fm < 4; ++fm)
#pragma unroll
      for (int fi = 0; fi < 5; ++fi) acc[cv][fm][fi] = (f32x4){0.f, 0.f, 0.f, 0.f};

  char* WsB = (char*)Wbuf;
  char* XsB = (char*)Xs;
  int wavebase = t & ~63;

  // prologue: zero halo/pad X cells ONCE (never rewritten); stage group (0,0) -> buf0
#pragma unroll
  for (int i = 0; i < 3; ++i) {
    if (xhas[i] && !xvalid[i]) {
      ushort8 pk;
#pragma unroll
      for (int j = 0; j < 8; ++j) pk[j] = 0;
      *(ushort8*)(XsB + (size_t)(i * 512 + t) * 16) = pk;
    }
  }
#pragma unroll
  for (int r = 0; r < 3; ++r) {
    size_t g16 = ((size_t)r * 32 + f0 + wid) * 64 + lane;
    gload_lds16(wtqB + g16 * 16, WsB + (size_t)(r * 2 + 0) * 8192 + wavebase * 16);
    gload_lds16(wtkB + g16 * 16, WsB + (size_t)(r * 2 + 1) * 8192 + wavebase * 16);
  }

  int buf = 0;
#pragma unroll 1
  for (int chunk = 0; chunk < 64; ++chunk) {
    int ic0 = chunk * 32;
    // X: load (transient regs) -> cvt -> LDS, valid cells only
    {
      float xv[3][8];
#pragma unroll
      for (int i = 0; i < 3; ++i)
        if (xvalid[i]) {
          const float* s = fb + (size_t)ic0 * kHW + xoff[i];
#pragma unroll
          for (int j = 0; j < 8; ++j) xv[i][j] = s[(size_t)j * kHW];
        }
#pragma unroll
      for (int i = 0; i < 3; ++i) {
        if (!xvalid[i]) continue;
        ushort8 pk;
#pragma unroll
        for (int j = 0; j < 8; ++j) pk[j] = f2bf(xv[i][j]);
        *(ushort8*)(XsB + (size_t)(i * 512 + t) * 16) = pk;
      }
    }
    __syncthreads();  // X visible + prior W staging drained

#pragma unroll 1
    for (int g = 0; g < 3; ++g) {
      // stage next 3-tap group into the other buffer
      bool hn = (g < 2) || (chunk < 63);
      if (hn) {
        int nchunk = (g < 2) ? chunk : chunk + 1;
        int ng     = (g < 2) ? g + 1 : 0;
#pragma unroll
        for (int r = 0; r < 3; ++r) {
          size_t g16 = ((size_t)(nchunk * 9 + ng * 3 + r) * 32 + f0 + wid) * 64 + lane;
          gload_lds16(wtqB + g16 * 16,
                      WsB + (size_t)((buf ^ 1) * 6 + r * 2 + 0) * 8192 + wavebase * 16);
          gload_lds16(wtkB + g16 * 16,
                      WsB + (size_t)((buf ^ 1) * 6 + r * 2 + 1) * 8192 + wavebase * 16);
        }
      }
      // compute current group: 3 taps x 2 convs x 4 fm x nfn
#pragma unroll
      for (int r = 0; r < 3; ++r) {
        int tap = g * 3 + r;
        int d16 = ((tap / 3 - 1) * 14 + (tap % 3 - 1)) * 16;
        bf16x8 af[2][4];
#pragma unroll
        for (int cv = 0; cv < 2; ++cv)
#pragma unroll
          for (int fm = 0; fm < 4; ++fm)
            af[cv][fm] = *(const bf16x8*)(WsB + (size_t)(buf * 6 + r * 2 + cv) * 8192 + aAddr[fm]);
#pragma unroll
        for (int fi = 0; fi < 5; ++fi) {
          if (fi >= nfn) continue;  // wave-uniform
          bf16x8 bb = *(const bf16x8*)(XsB + bAddr[fi] + d16);
#pragma unroll
          for (int cv = 0; cv < 2; ++cv)
#pragma unroll
            for (int fm = 0; fm < 4; ++fm)
              acc[cv][fm][fi] =
                  __builtin_amdgcn_mfma_f32_16x16x32_bf16(af[cv][fm], bb, acc[cv][fm][fi], 0, 0, 0);
        }
      }
      __syncthreads();  // all waves done with buf; next staging drained at next barrier
      buf ^= 1;
    }
  }

  // epilogue: C row(oc) = kg*4+reg (+fm*16+wm*64), col(p) = l15 (+frag base)
#pragma unroll
  for (int cv = 0; cv < 2; ++cv) {
    float* outp = cv ? fko : fqo;
    const float* bias = cv ? kb : qb;
#pragma unroll
    for (int fi = 0; fi < 5; ++fi) {
      if (fi >= nfn) continue;
      int p = (fnb + fi) * 16 + l15;
#pragma unroll
      for (int fm = 0; fm < 4; ++fm)
#pragma unroll
        for (int reg = 0; reg < 4; ++reg) {
          int oc = oc0 + wm * 64 + fm * 16 + kg * 4 + reg;
          outp[((size_t)b * kCQ + oc) * kHW + p] = acc[cv][fm][fi][reg] + bias[oc];
        }
    }
  }
}

// -------- warp GEMM via MFMA: W[c,q] = sum_k tgt[c,k]*pr[q,k] + recon + dist^2 --------
__global__ __launch_bounds__(512) void warp_mfma_kernel(const float* __restrict__ fv,
                                                        const float* __restrict__ ft,
                                                        const unsigned short* __restrict__ prb,
                                                        const float* __restrict__ maskp,
                                                        const int* __restrict__ idx,
                                                        float* __restrict__ outp,
                                                        float* __restrict__ dsq,
                                                        int write_out) {
  __shared__ unsigned short AsHi[128 * 32];
  __shared__ unsigned short AsLo[128 * 32];
  __shared__ unsigned short Bs[288 * 32];
  int t    = threadIdx.x;
  int lane = t & 63;
  int wid  = t >> 6;
  int l15  = lane & 15, kg = lane >> 4;
  int wm   = wid >> 1, wn = wid & 1;
  int c0   = blockIdx.x * 128;
  int b    = blockIdx.y;
  int tb   = idx[b];
  const float* tgt = feat_base(fv, ft, tb);
  const float* fb  = feat_base(fv, ft, b);

  int ar = t >> 2, as = t & 3;
  int aslot = as ^ ((ar ^ (ar >> 2)) & 3);
  unsigned short* aDstHi = AsHi + ar * 32 + aslot * 8;
  unsigned short* aDstLo = AsLo + ar * 32 + aslot * 8;

  int aIdx[2];
#pragma unroll
  for (int fm = 0; fm < 2; ++fm) {
    int r = wm * 32 + fm * 16 + l15;
    aIdx[fm] = r * 32 + (kg ^ ((r ^ (r >> 2)) & 3)) * 8;
  }
  int bIdx[9];
#pragma unroll
  for (int fn = 0; fn < 9; ++fn) {
    int q = wn * 144 + fn * 16 + l15;
    bIdx[fn] = q * 32 + (kg ^ ((q ^ (q >> 2)) & 3)) * 8;
  }

  f32x4 acc[2][9];
#pragma unroll
  for (int fm = 0; fm < 2; ++fm)
#pragma unroll
    for (int fn = 0; fn < 9; ++fn) acc[fm][fn] = (f32x4){0.f, 0.f, 0.f, 0.f};

#pragma unroll 1
  for (int chunk = 0; chunk < 9; ++chunk) {
    int k0 = chunk * 32;
    __syncthreads();
    {
      const float* s = tgt + (size_t)(c0 + ar) * kHW + k0 + as * 8;
      float4 v0 = *(const float4*)(s);
      float4 v1 = *(const float4*)(s + 4);
      float xs[8] = {v0.x, v0.y, v0.z, v0.w, v1.x, v1.y, v1.z, v1.w};
      ushort8 hi, lo;
#pragma unroll
      for (int j = 0; j < 8; ++j) {
        unsigned short h = f2bf(xs[j]);
        hi[j] = h;
        lo[j] = f2bf(xs[j] - bf2f(h));
      }
      *(ushort8*)aDstHi = hi;
      *(ushort8*)aDstLo = lo;
    }
#pragma unroll
    for (int i = 0; i < 3; ++i) {
      int item = i * 512 + t;
      if (item < 1152) {
        int q = item >> 2, s = item & 3;
        ushort8 v = *(const ushort8*)(prb + ((size_t)b * kHW + q) * kHW + k0 + s * 8);
        *(ushort8*)(Bs + q * 32 + (s ^ ((q ^ (q >> 2)) & 3)) * 8) = v;
      }
    }
    __syncthreads();
    bf16x8 ah0 = *(const bf16x8*)(AsHi + aIdx[0]);
    bf16x8 al0 = *(const bf16x8*)(AsLo + aIdx[0]);
    bf16x8 ah1 = *(const bf16x8*)(AsHi + aIdx[1]);
    bf16x8 al1 = *(const bf16x8*)(AsLo + aIdx[1]);
#pragma unroll
    for (int fn = 0; fn < 9; ++fn) {
      bf16x8 bb = *(const bf16x8*)(Bs + bIdx[fn]);
      acc[0][fn] = __builtin_amdgcn_mfma_f32_16x16x32_bf16(ah0, bb, acc[0][fn], 0, 0, 0);
      acc[0][fn] = __builtin_amdgcn_mfma_f32_16x16x32_bf16(al0, bb, acc[0][fn], 0, 0, 0);
      acc[1][fn] = __builtin_amdgcn_mfma_f32_16x16x32_bf16(ah1, bb, acc[1][fn], 0, 0, 0);
      acc[1][fn] = __builtin_amdgcn_mfma_f32_16x16x32_bf16(al1, bb, acc[1][fn], 0, 0, 0);
    }
  }

#pragma unroll
  for (int fn = 0; fn < 9; ++fn) {
    int q = wn * 144 + fn * 16 + l15;
    float mj = maskp[b * kHW + q];
    float psum = 0.f;
#pragma unroll
    for (int fm = 0; fm < 2; ++fm) {
#pragma unroll
      for (int reg = 0; reg < 4; ++reg) {
        int c = c0 + wm * 32 + fm * 16 + kg * 4 + reg;
        float fvv = fb[(size_t)c * kHW + q];
        float Wv  = acc[fm][fn][reg];
        float d   = mj * (fvv - Wv) + 1e-6f;
        psum      = fmaf(d, d, psum);
        if (write_out)
          outp[((size_t)b * kC + c) * kHW + q] = mj * Wv + (1.f - mj) * fvv;
      }
    }
    psum += __shfl_xor(psum, 16);
    psum += __shfl_xor(psum, 32);
    if (lane < 16) atomicAdd(&dsq[b * kHW + q], psum);
  }
}

// -------- mask pass 1: partial channel sum-of-squares over 512-c slices --------
__global__ __launch_bounds__(320) void mask_part_kernel(const float* __restrict__ fv,
                                                        const float* __restrict__ ft,
                                                        float* __restrict__ part) {
  int b = blockIdx.x;
  int s = blockIdx.y;
  int t = threadIdx.x;
  if (t >= kHW) return;
  const float* fb = feat_base(fv, ft, b) + (size_t)(s * 512) * kHW;
  float sum = 0.f;
  for (int c = 0; c < 512; ++c) { float v = fb[(size_t)c * kHW + t]; sum += v * v; }
  part[((size_t)b * 4 + s) * kHW + t] = sum;
}

// -------- mask pass 2: finalize sqrt + per-sample min-max normalize --------
__global__ __launch_bounds__(320) void mask_fin_kernel(const float* __restrict__ part,
                                                       float* __restrict__ mask) {
  int b = blockIdx.x;
  int t = threadIdx.x;
  float n = 0.f;
  if (t < kHW) {
    const float* pb = part + (size_t)b * 4 * kHW;
    n = sqrtf(pb[t] + pb[kHW + t] + pb[2 * kHW + t] + pb[3 * kHW + t]);
  }
  __shared__ float sh[320];
  sh[t] = (t < kHW) ? n : 3.4e38f;
  __syncthreads();
  float mn;
  {
    float m = 3.4e38f;
    if (t < 64) {
      for (int i = t; i < 320; i += 64) m = fminf(m, sh[i]);
      for (int off = 32; off; off >>= 1) m = fminf(m, __shfl_xor(m, off));
    }
    __syncthreads();
    if (t == 0) sh[0] = m;
    __syncthreads();
    mn = sh[0];
    __syncthreads();
  }
  sh[t] = (t < kHW) ? n : -3.4e38f;
  __syncthreads();
  float mx;
  {
    float m = -3.4e38f;
    if (t < 64) {
      for (int i = t; i < 320; i += 64) m = fmaxf(m, sh[i]);
      for (int off = 32; off; off >>= 1) m = fmaxf(m, __shfl_xor(m, off));
    }
    __syncthreads();
    if (t == 0) sh[0] = m;
    __syncthreads();
    mx = sh[0];
  }
  if (t < kHW) mask[b * kHW + t] = (n - mn) / ((mx - mn) + 1e-12f);
}

// -------- per-(b,pos) inverse L2 norm over projected channels --------
__global__ __launch_bounds__(320) void norminv_kernel(const float* __restrict__ fq,
                                                      const float* __restrict__ fk,
                                                      float* __restrict__ qinv,
                                                      float* __restrict__ kinv) {
  int b = blockIdx.x;
  int z = blockIdx.y;
  const float* src = z ? fk : fq;
  float* dst       = z ? kinv : qinv;
  int t = threadIdx.x;
  if (t >= kHW) return;
  const float* sb = src + (size_t)b * kCQ * kHW;
  float s = 0.f;
  for (int c = 0; c < kCQ; ++c) { float v = sb[(size_t)c * kHW + t]; s += v * v; }
  float n = sqrtf(s);
  dst[b * kHW + t] = 1.f / fmaxf(n, 1e-12f);
}

// -------- FUSED sim + softmax: logits in-block, row softmax via LDS transpose --------
// block (q0 group of 32 q, b); thread t = k. S[32][289] padded (conflict-free).
__global__ __launch_bounds__(320) void sim_softmax_kernel(const float* __restrict__ fq,
                                                          const float* __restrict__ fk,
                                                          const float* __restrict__ qinv,
                                                          const float* __restrict__ kinv,
                                                          const int* __restrict__ idx,
                                                          unsigned short* __restrict__ prb) {
  __shared__ float S[32][289];
  int b  = blockIdx.y;
  int q0 = blockIdx.x * 32;
  int t  = threadIdx.x;
  int tb = idx[b];
  if (t < kHW) {
    const float* fqb = fq + (size_t)b * kCQ * kHW + q0;
    const float* fkb = fk + (size_t)tb * kCQ * kHW;
    float acc[32];
#pragma unroll
    for (int q = 0; q < 32; ++q) acc[q] = 0.f;
#pragma unroll 1
    for (int c = 0; c < kCQ; ++c) {
      float kv = fkb[(size_t)c * kHW + t];
#pragma unroll
      for (int q = 0; q < 32; ++q) acc[q] = fmaf(fqb[(size_t)c * kHW + q], kv, acc[q]);
    }
    float ks = kinv[tb * kHW + t];
#pragma unroll
    for (int q = 0; q < 32; ++q)
      S[q][t] = kTemp * qinv[b * kHW + q0 + q] * ks * acc[q];
  }
  __syncthreads();
  // per-row softmax: wave w handles rows q = w, w+5, ...
  int w = t >> 6, l = t & 63;
  for (int q = w; q < 32; q += 5) {
    float v[5];
    float m = -3.4e38f;
#pragma unroll
    for (int j = 0; j < 5; ++j) {
      int k = l + 64 * j;
      v[j] = (k < kHW) ? S[q][k] : -3.4e38f;
      m = fmaxf(m, v[j]);
    }
    for (int off = 32; off; off >>= 1) m = fmaxf(m, __shfl_xor(m, off));
    float e[5];
    float s = 0.f;
#pragma unroll
    for (int j = 0; j < 5; ++j) {
      int k = l + 64 * j;
      e[j] = (k < kHW) ? __expf(v[j] - m) : 0.f;
      s += e[j];
    }
    for (int off = 32; off; off >>= 1) s += __shfl_xor(s, off);
    float inv = 1.f / s;
    unsigned short* row = prb + ((size_t)b * kHW + q0 + q) * kHW;
#pragma unroll
    for (int j = 0; j < 5; ++j) {
      int k = l + 64 * j;
      if (k < kHW) row[k] = f2bf(e[j] * inv);
    }
  }
}

// -------- comask (reads bf16 pr) --------
__global__ __launch_bounds__(320) void comask_kernel(const unsigned short* __restrict__ prb,
                                                     const float* __restrict__ mask,
                                                     const int* __restrict__ idx,
                                                     float* __restrict__ comask) {
  int b = blockIdx.x;
  int t = threadIdx.x;
  int tb = idx[b];
  __shared__ float mt[kHW];
  __shared__ float cm[kHW];
  __shared__ float red[320];
  if (t < kHW) mt[t] = mask[tb * kHW + t];
  __syncthreads();
  int wv = t >> 6, l = t & 63;
  for (int q = wv; q < kHW; q += 5) {
    const unsigned short* prow = prb + ((size_t)b * kHW + q) * kHW;
    float s = 0.f;
    for (int k = l; k < kHW; k += 64) s += bf2f(prow[k]) * mt[k];
    for (int off = 32; off; off >>= 1) s += __shfl_xor(s, off);
    if (l == 0) cm[q] = mask[b * kHW + q] * s;
  }
  __syncthreads();
  float v = (t < kHW) ? cm[t] : 0.f;
  red[t] = (t < kHW) ? v : 3.4e38f;
  __syncthreads();
  float mn;
  {
    float m = 3.4e38f;
    if (t < 64) {
      for (int i = t; i < 320; i += 64) m = fminf(m, red[i]);
      for (int off = 32; off; off >>= 1) m = fminf(m, __shfl_xor(m, off));
    }
    __syncthreads();
    if (t == 0) red[0] = m;
    __syncthreads();
    mn = red[0];
    __syncthreads();
  }
  red[t] = (t < kHW) ? v : -3.4e38f;
  __syncthreads();
  float mx;
  {
    float m = -3.4e38f;
    if (t < 64) {
      for (int i = t; i < 320; i += 64) m = fmaxf(m, red[i]);
      for (int off = 32; off; off >>= 1) m = fmaxf(m, __shfl_xor(m, off));
    }
    __syncthreads();
    if (t == 0) red[0] = m;
    __syncthreads();
    mx = red[0];
  }
  if (t < kHW) comask[b * kHW + t] = (v - mn) / ((mx - mn) + 1e-12f);
}

// -------- triplet loss --------
__global__ __launch_bounds__(256) void loss_kernel(const float* __restrict__ dap,
                                                   const float* __restrict__ dan,
                                                   const float* __restrict__ comask,
                                                   float* __restrict__ out) {
  int t = threadIdx.x;
  float s = 0.f;
  for (int i = t; i < kB * kHW; i += 256) {
    float da = sqrtf(dap[i]);
    float db = sqrtf(dan[i]);
    float tr = fmaxf(da - db + 0.3f, 0.f);
    s += comask[i] * tr;
  }
  for (int off = 32; off; off >>= 1) s += __shfl_xor(s, off);
  __shared__ float sh[4];
  if ((t & 63) == 0) sh[t >> 6] = s;
  __syncthreads();
  if (t == 0)
    out[(size_t)kB * kC * kHW] = (sh[0] + sh[1] + sh[2] + sh[3]) * (1.f / (float)(kB * kHW));
}

extern "C" void kernel_launch(void* const* d_in, const int* in_sizes, int n_in,
                              void* d_out, int out_size, void* d_ws, size_t ws_size,
                              hipStream_t stream) {
  const float* fv = (const float*)d_in[0];
  const float* ft = (const float*)d_in[1];
  const float* qw = (const float*)d_in[4];
  const float* qb = (const float*)d_in[5];
  const float* kw = (const float*)d_in[6];
  const float* kb = (const float*)d_in[7];
  const int* pos_idx = (const int*)d_in[8];
  const int* neg_idx = (const int*)d_in[9];
  float* out = (float*)d_out;

  constexpr size_t kFQ = (size_t)kB * kCQ * kHW;
  float* ws   = (float*)d_ws;
  float* fq   = ws;
  float* fk   = fq + kFQ;
  unsigned short* wtq = (unsigned short*)(fk + kFQ);
  unsigned short* wtk = wtq + (size_t)9 * kCQ * kC;
  unsigned short* prb = wtq;                               // alias: bf16 P, live after convs
  float* part = (float*)wtq;                               // alias: mask partials, dead before prep_w
  float* maskb   = (float*)(wtk + (size_t)9 * kCQ * kC);
  float* qinv    = maskb + kB * kHW;
  float* kinv    = qinv + kB * kHW;
  float* comaskb = kinv + kB * kHW;
  float* dap     = comaskb + kB * kHW;
  float* dan     = dap + kB * kHW;
  if (ws_size < (size_t)113688576) return;

  zero_kernel<<<dim3((2 * kB * kHW + 255) / 256), 256, 0, stream>>>(dap, 2 * kB * kHW);
  mask_part_kernel<<<dim3(kB, 4), 320, 0, stream>>>(fv, ft, part);
  mask_fin_kernel<<<dim3(kB), 320, 0, stream>>>(part, maskb);
  prep_w_kernel<<<dim3(kCQ, 2), 256, 0, stream>>>(qw, kw, wtq, wtk);
  conv_fused_kernel<<<dim3(256), 512, 0, stream>>>(wtq, wtk, qb, kb, fv, ft, fq, fk);
  norminv_kernel<<<dim3(kB, 2), 320, 0, stream>>>(fq, fk, qinv, kinv);

  // positive branch (prb overwrites wt region — weights dead now)
  sim_softmax_kernel<<<dim3(9, kB), 320, 0, stream>>>(fq, fk, qinv, kinv, pos_idx, prb);
  comask_kernel<<<dim3(kB), 320, 0, stream>>>(prb, maskb, pos_idx, comaskb);
  warp_mfma_kernel<<<dim3(16, kB), 512, 0, stream>>>(fv, ft, prb, maskb, pos_idx, out, dap, 1);

  // negative branch
  sim_softmax_kernel<<<dim3(9, kB), 320, 0, stream>>>(fq, fk, qinv, kinv, neg_idx, prb);
  warp_mfma_kernel<<<dim3(16, kB), 512, 0, stream>>>(fv, ft, prb, maskb, neg_idx, out, dan, 0);

  loss_kernel<<<dim3(1), 256, 0, stream>>>(dap, dan, comaskb, out);
}

// Round 15
// 1269.538 us; speedup vs baseline: 2.2870x; 1.2067x over previous
//
#include <hip/hip_runtime.h>
#include <cstdint>
#include <cstddef>

// CMAlign forward. R15: sim -> MFMA. norm_transpose produces normalized bf16
// fqT/fkT [b][p][c]; sim_mfma computes 50*QK^T via 16x16x32 MFMA + in-block softmax.
// Conv untouched (R11 best, 628us). Shapes: B=64, C=2048, Cq=512, H=24, W=12, HW=288.

namespace {
constexpr int kB    = 64;
constexpr int kHalf = 32;
constexpr int kC    = 2048;
constexpr int kCQ   = 512;
constexpr int kH    = 24;
constexpr int kW    = 12;
constexpr int kHW   = 288;
constexpr float kTemp = 50.0f;
constexpr int kXPlane = 366;  // 16B cells; 5856 B = 96 mod 128 -> kg quadrant offsets
}

typedef __attribute__((ext_vector_type(8))) __bf16 bf16x8;
typedef __attribute__((ext_vector_type(4))) float f32x4;
typedef __attribute__((ext_vector_type(8))) unsigned short ushort8;

__device__ __forceinline__ const float* feat_base(const float* fv, const float* ft, int b) {
  return (b < kHalf) ? (fv + (size_t)b * kC * kHW)
                     : (ft + (size_t)(b - kHalf) * kC * kHW);
}

__device__ __forceinline__ unsigned short f2bf(float f) {
  union { float f; unsigned u; } c; c.f = f;
  unsigned u = c.u;
  unsigned r = (u + 0x7FFFu + ((u >> 16) & 1u)) >> 16;  // RNE
  return (unsigned short)r;
}

__device__ __forceinline__ float bf2f(unsigned short h) {
  union { unsigned u; float f; } c; c.u = ((unsigned)h) << 16;
  return c.f;
}

__device__ __forceinline__ void gload_lds16(const void* g, void* l) {
  __builtin_amdgcn_global_load_lds(
      (const __attribute__((address_space(1))) unsigned int*)g,
      (__attribute__((address_space(3))) unsigned int*)l, 16, 0, 0);
}

__global__ void zero_kernel(float* __restrict__ p, int n) {
  int i = blockIdx.x * 256 + threadIdx.x;
  if (i < n) p[i] = 0.f;
}

// -------- weight prep: w[oc][ic][3][3] fp32 -> MFMA-image wt2 --------
__global__ __launch_bounds__(256) void prep_w_kernel(const float* __restrict__ qw,
                                                     const float* __restrict__ kw,
                                                     unsigned short* __restrict__ wtq,
                                                     unsigned short* __restrict__ wtk) {
  int oc = blockIdx.x;
  int z  = blockIdx.y;
  const float* w = (z ? kw : qw) + (size_t)oc * (kC * 9);
  unsigned short* wt = z ? wtk : wtq;
  __shared__ unsigned short lw[kC * 9];  // [ic][tap]
  int t = threadIdx.x;
#pragma unroll
  for (int it = 0; it < 18; ++it) {
    int i4 = (it * 256 + t) * 4;
    float4 v = *(const float4*)(w + i4);
    lw[i4 + 0] = f2bf(v.x);
    lw[i4 + 1] = f2bf(v.y);
    lw[i4 + 2] = f2bf(v.z);
    lw[i4 + 3] = f2bf(v.w);
  }
  __syncthreads();
  for (int item = t; item < 9 * 256; item += 256) {
    int tap = item >> 8;
    int icb = item & 255;
    ushort8 pk;
#pragma unroll
    for (int j = 0; j < 8; ++j) pk[j] = lw[(icb * 8 + j) * 9 + tap];
    size_t dst16 = (((size_t)(icb >> 2) * 9 + tap) * 32 + (oc >> 4)) * 64
                   + (oc & 15) + (icb & 3) * 16;
    *(ushort8*)(wt + dst16 * 8) = pk;
  }
}

// -------- FUSED MFMA conv (R11 structure, unchanged) --------
__global__ __launch_bounds__(512, 1) void conv_fused_kernel(const unsigned short* __restrict__ wtq,
                                                            const unsigned short* __restrict__ wtk,
                                                            const float* __restrict__ qb,
                                                            const float* __restrict__ kb,
                                                            const float* __restrict__ fv,
                                                            const float* __restrict__ ft,
                                                            float* __restrict__ fqo,
                                                            float* __restrict__ fko) {
  __shared__ unsigned short Wbuf[2 * 6 * 4096];   // 98304 B
  __shared__ unsigned short Xs[4 * kXPlane * 8];  // 23424 B
  int t    = threadIdx.x;
  int lane = t & 63;
  int wid  = t >> 6;
  int l15  = lane & 15, kg = lane >> 4;
  int wm   = wid & 1, wn = wid >> 1;  // 2M x 4N
  int n    = blockIdx.x;
  int xcd  = n & 7;
  int oc0  = (xcd >> 1) * 128;
  int b    = ((xcd & 1) << 5) + (n >> 3);
  int f0   = oc0 >> 4;
  const float* fb = feat_base(fv, ft, b);
  const char* wtqB = (const char*)wtq;
  const char* wtkB = (const char*)wtk;

  int  xoff[3];
  bool xvalid[3], xhas[3];
#pragma unroll
  for (int i = 0; i < 3; ++i) {
    int item = i * 512 + t;
    xhas[i] = item < 4 * kXPlane;
    int xkg = item / kXPlane;
    int hp  = item - xkg * kXPlane;
    int hy = hp / 14, hx = hp - hy * 14;
    int y = hy - 1, x = hx - 1;
    bool v = xhas[i] && hp < 364 && (y >= 0 && y < kH && x >= 0 && x < kW);
    xvalid[i] = v;
    xoff[i] = v ? (xkg * 8) * kHW + y * kW + x : 0;
  }

  int aAddr[4];
#pragma unroll
  for (int fm = 0; fm < 4; ++fm)
    aAddr[fm] = (((wm * 4 + fm) * 64) + lane) * 16;
  int nfn = (wn < 2) ? 5 : 4;
  int fnb = (wn < 2) ? wn * 5 : 10 + (wn - 2) * 4;
  int bAddr[5];
#pragma unroll
  for (int fi = 0; fi < 5; ++fi) {
    int p = (fnb + fi) * 16 + l15;
    if (p > 287) p = 287;
    int y = p / kW, x = p - y * kW;
    bAddr[fi] = kg * (kXPlane * 16) + ((y + 1) * 14 + (x + 1)) * 16;
  }

  f32x4 acc[2][4][5];
#pragma unroll
  for (int cv = 0; cv < 2; ++cv)
#pragma unroll
    for (int fm = 0; fm < 4; ++fm)
#pragma unroll
      for (int fi = 0; fi < 5; ++fi) acc[cv][fm][fi] = (f32x4){0.f, 0.f, 0.f, 0.f};

  char* WsB = (char*)Wbuf;
  char* XsB = (char*)Xs;
  int wavebase = t & ~63;

#pragma unroll
  for (int i = 0; i < 3; ++i) {
    if (xhas[i] && !xvalid[i]) {
      ushort8 pk;
#pragma unroll
      for (int j = 0; j < 8; ++j) pk[j] = 0;
      *(ushort8*)(XsB + (size_t)(i * 512 + t) * 16) = pk;
    }
  }
#pragma unroll
  for (int r = 0; r < 3; ++r) {
    size_t g16 = ((size_t)r * 32 + f0 + wid) * 64 + lane;
    gload_lds16(wtqB + g16 * 16, WsB + (size_t)(r * 2 + 0) * 8192 + wavebase * 16);
    gload_lds16(wtkB + g16 * 16, WsB + (size_t)(r * 2 + 1) * 8192 + wavebase * 16);
  }

  int buf = 0;
#pragma unroll 1
  for (int chunk = 0; chunk < 64; ++chunk) {
    int ic0 = chunk * 32;
    {
      float xv[3][8];
#pragma unroll
      for (int i = 0; i < 3; ++i)
        if (xvalid[i]) {
          const float* s = fb + (size_t)ic0 * kHW + xoff[i];
#pragma unroll
          for (int j = 0; j < 8; ++j) xv[i][j] = s[(size_t)j * kHW];
        }
#pragma unroll
      for (int i = 0; i < 3; ++i) {
        if (!xvalid[i]) continue;
        ushort8 pk;
#pragma unroll
        for (int j = 0; j < 8; ++j) pk[j] = f2bf(xv[i][j]);
        *(ushort8*)(XsB + (size_t)(i * 512 + t) * 16) = pk;
      }
    }
    __syncthreads();

#pragma unroll 1
    for (int g = 0; g < 3; ++g) {
      bool hn = (g < 2) || (chunk < 63);
      if (hn) {
        int nchunk = (g < 2) ? chunk : chunk + 1;
        int ng     = (g < 2) ? g + 1 : 0;
#pragma unroll
        for (int r = 0; r < 3; ++r) {
          size_t g16 = ((size_t)(nchunk * 9 + ng * 3 + r) * 32 + f0 + wid) * 64 + lane;
          gload_lds16(wtqB + g16 * 16,
                      WsB + (size_t)((buf ^ 1) * 6 + r * 2 + 0) * 8192 + wavebase * 16);
          gload_lds16(wtkB + g16 * 16,
                      WsB + (size_t)((buf ^ 1) * 6 + r * 2 + 1) * 8192 + wavebase * 16);
        }
      }
#pragma unroll
      for (int r = 0; r < 3; ++r) {
        int tap = g * 3 + r;
        int d16 = ((tap / 3 - 1) * 14 + (tap % 3 - 1)) * 16;
        bf16x8 af[2][4];
#pragma unroll
        for (int cv = 0; cv < 2; ++cv)
#pragma unroll
          for (int fm = 0; fm < 4; ++fm)
            af[cv][fm] = *(const bf16x8*)(WsB + (size_t)(buf * 6 + r * 2 + cv) * 8192 + aAddr[fm]);
#pragma unroll
        for (int fi = 0; fi < 5; ++fi) {
          if (fi >= nfn) continue;
          bf16x8 bb = *(const bf16x8*)(XsB + bAddr[fi] + d16);
#pragma unroll
          for (int cv = 0; cv < 2; ++cv)
#pragma unroll
            for (int fm = 0; fm < 4; ++fm)
              acc[cv][fm][fi] =
                  __builtin_amdgcn_mfma_f32_16x16x32_bf16(af[cv][fm], bb, acc[cv][fm][fi], 0, 0, 0);
        }
      }
      __syncthreads();
      buf ^= 1;
    }
  }

#pragma unroll
  for (int cv = 0; cv < 2; ++cv) {
    float* outp = cv ? fko : fqo;
    const float* bias = cv ? kb : qb;
#pragma unroll
    for (int fi = 0; fi < 5; ++fi) {
      if (fi >= nfn) continue;
      int p = (fnb + fi) * 16 + l15;
#pragma unroll
      for (int fm = 0; fm < 4; ++fm)
#pragma unroll
        for (int reg = 0; reg < 4; ++reg) {
          int oc = oc0 + wm * 64 + fm * 16 + kg * 4 + reg;
          outp[((size_t)b * kCQ + oc) * kHW + p] = acc[cv][fm][fi][reg] + bias[oc];
        }
    }
  }
}

// -------- warp GEMM via MFMA (unchanged) --------
__global__ __launch_bounds__(512) void warp_mfma_kernel(const float* __restrict__ fv,
                                                        const float* __restrict__ ft,
                                                        const unsigned short* __restrict__ prb,
                                                        const float* __restrict__ maskp,
                                                        const int* __restrict__ idx,
                                                        float* __restrict__ outp,
                                                        float* __restrict__ dsq,
                                                        int write_out) {
  __shared__ unsigned short AsHi[128 * 32];
  __shared__ unsigned short AsLo[128 * 32];
  __shared__ unsigned short Bs[288 * 32];
  int t    = threadIdx.x;
  int lane = t & 63;
  int wid  = t >> 6;
  int l15  = lane & 15, kg = lane >> 4;
  int wm   = wid >> 1, wn = wid & 1;
  int c0   = blockIdx.x * 128;
  int b    = blockIdx.y;
  int tb   = idx[b];
  const float* tgt = feat_base(fv, ft, tb);
  const float* fb  = feat_base(fv, ft, b);

  int ar = t >> 2, as = t & 3;
  int aslot = as ^ ((ar ^ (ar >> 2)) & 3);
  unsigned short* aDstHi = AsHi + ar * 32 + aslot * 8;
  unsigned short* aDstLo = AsLo + ar * 32 + aslot * 8;

  int aIdx[2];
#pragma unroll
  for (int fm = 0; fm < 2; ++fm) {
    int r = wm * 32 + fm * 16 + l15;
    aIdx[fm] = r * 32 + (kg ^ ((r ^ (r >> 2)) & 3)) * 8;
  }
  int bIdx[9];
#pragma unroll
  for (int fn = 0; fn < 9; ++fn) {
    int q = wn * 144 + fn * 16 + l15;
    bIdx[fn] = q * 32 + (kg ^ ((q ^ (q >> 2)) & 3)) * 8;
  }

  f32x4 acc[2][9];
#pragma unroll
  for (int fm = 0; fm < 2; ++fm)
#pragma unroll
    for (int fn = 0; fn < 9; ++fn) acc[fm][fn] = (f32x4){0.f, 0.f, 0.f, 0.f};

#pragma unroll 1
  for (int chunk = 0; chunk < 9; ++chunk) {
    int k0 = chunk * 32;
    __syncthreads();
    {
      const float* s = tgt + (size_t)(c0 + ar) * kHW + k0 + as * 8;
      float4 v0 = *(const float4*)(s);
      float4 v1 = *(const float4*)(s + 4);
      float xs[8] = {v0.x, v0.y, v0.z, v0.w, v1.x, v1.y, v1.z, v1.w};
      ushort8 hi, lo;
#pragma unroll
      for (int j = 0; j < 8; ++j) {
        unsigned short h = f2bf(xs[j]);
        hi[j] = h;
        lo[j] = f2bf(xs[j] - bf2f(h));
      }
      *(ushort8*)aDstHi = hi;
      *(ushort8*)aDstLo = lo;
    }
#pragma unroll
    for (int i = 0; i < 3; ++i) {
      int item = i * 512 + t;
      if (item < 1152) {
        int q = item >> 2, s = item & 3;
        ushort8 v = *(const ushort8*)(prb + ((size_t)b * kHW + q) * kHW + k0 + s * 8);
        *(ushort8*)(Bs + q * 32 + (s ^ ((q ^ (q >> 2)) & 3)) * 8) = v;
      }
    }
    __syncthreads();
    bf16x8 ah0 = *(const bf16x8*)(AsHi + aIdx[0]);
    bf16x8 al0 = *(const bf16x8*)(AsLo + aIdx[0]);
    bf16x8 ah1 = *(const bf16x8*)(AsHi + aIdx[1]);
    bf16x8 al1 = *(const bf16x8*)(AsLo + aIdx[1]);
#pragma unroll
    for (int fn = 0; fn < 9; ++fn) {
      bf16x8 bb = *(const bf16x8*)(Bs + bIdx[fn]);
      acc[0][fn] = __builtin_amdgcn_mfma_f32_16x16x32_bf16(ah0, bb, acc[0][fn], 0, 0, 0);
      acc[0][fn] = __builtin_amdgcn_mfma_f32_16x16x32_bf16(al0, bb, acc[0][fn], 0, 0, 0);
      acc[1][fn] = __builtin_amdgcn_mfma_f32_16x16x32_bf16(ah1, bb, acc[1][fn], 0, 0, 0);
      acc[1][fn] = __builtin_amdgcn_mfma_f32_16x16x32_bf16(al1, bb, acc[1][fn], 0, 0, 0);
    }
  }

#pragma unroll
  for (int fn = 0; fn < 9; ++fn) {
    int q = wn * 144 + fn * 16 + l15;
    float mj = maskp[b * kHW + q];
    float psum = 0.f;
#pragma unroll
    for (int fm = 0; fm < 2; ++fm) {
#pragma unroll
      for (int reg = 0; reg < 4; ++reg) {
        int c = c0 + wm * 32 + fm * 16 + kg * 4 + reg;
        float fvv = fb[(size_t)c * kHW + q];
        float Wv  = acc[fm][fn][reg];
        float d   = mj * (fvv - Wv) + 1e-6f;
        psum      = fmaf(d, d, psum);
        if (write_out)
          outp[((size_t)b * kC + c) * kHW + q] = mj * Wv + (1.f - mj) * fvv;
      }
    }
    psum += __shfl_xor(psum, 16);
    psum += __shfl_xor(psum, 32);
    if (lane < 16) atomicAdd(&dsq[b * kHW + q], psum);
  }
}

// -------- mask pass 1: partial channel sum-of-squares over 512-c slices --------
__global__ __launch_bounds__(320) void mask_part_kernel(const float* __restrict__ fv,
                                                        const float* __restrict__ ft,
                                                        float* __restrict__ part) {
  int b = blockIdx.x;
  int s = blockIdx.y;
  int t = threadIdx.x;
  if (t >= kHW) return;
  const float* fb = feat_base(fv, ft, b) + (size_t)(s * 512) * kHW;
  float sum = 0.f;
  for (int c = 0; c < 512; ++c) { float v = fb[(size_t)c * kHW + t]; sum += v * v; }
  part[((size_t)b * 4 + s) * kHW + t] = sum;
}

// -------- mask pass 2: finalize sqrt + per-sample min-max normalize --------
__global__ __launch_bounds__(320) void mask_fin_kernel(const float* __restrict__ part,
                                                       float* __restrict__ mask) {
  int b = blockIdx.x;
  int t = threadIdx.x;
  float n = 0.f;
  if (t < kHW) {
    const float* pb = part + (size_t)b * 4 * kHW;
    n = sqrtf(pb[t] + pb[kHW + t] + pb[2 * kHW + t] + pb[3 * kHW + t]);
  }
  __shared__ float sh[320];
  sh[t] = (t < kHW) ? n : 3.4e38f;
  __syncthreads();
  float mn;
  {
    float m = 3.4e38f;
    if (t < 64) {
      for (int i = t; i < 320; i += 64) m = fminf(m, sh[i]);
      for (int off = 32; off; off >>= 1) m = fminf(m, __shfl_xor(m, off));
    }
    __syncthreads();
    if (t == 0) sh[0] = m;
    __syncthreads();
    mn = sh[0];
    __syncthreads();
  }
  sh[t] = (t < kHW) ? n : -3.4e38f;
  __syncthreads();
  float mx;
  {
    float m = -3.4e38f;
    if (t < 64) {
      for (int i = t; i < 320; i += 64) m = fmaxf(m, sh[i]);
      for (int off = 32; off; off >>= 1) m = fmaxf(m, __shfl_xor(m, off));
    }
    __syncthreads();
    if (t == 0) sh[0] = m;
    __syncthreads();
    mx = sh[0];
  }
  if (t < kHW) mask[b * kHW + t] = (n - mn) / ((mx - mn) + 1e-12f);
}

// -------- norm + transpose: fq[b][c][p] fp32 -> fqT[b][p][c] bf16, L2-normalized over c --------
// grid (64 b, 2 z); inv-norms in LDS (phase 1), then 32x32 LDS-tile transpose (phase 2).
__global__ __launch_bounds__(320) void norm_transpose_kernel(const float* __restrict__ fq,
                                                             const float* __restrict__ fk,
                                                             unsigned short* __restrict__ fqT,
                                                             unsigned short* __restrict__ fkT) {
  int b = blockIdx.x, z = blockIdx.y;
  const float* src = (z ? fk : fq) + (size_t)b * kCQ * kHW;
  unsigned short* dst = (z ? fkT : fqT) + (size_t)b * kHW * kCQ;
  __shared__ float inv[kHW];
  __shared__ float Lt[32][33];
  int t = threadIdx.x;
  if (t < kHW) {
    float s = 0.f;
    for (int c = 0; c < kCQ; ++c) { float v = src[(size_t)c * kHW + t]; s += v * v; }
    inv[t] = 1.f / fmaxf(sqrtf(s), 1e-12f);
  }
  __syncthreads();
  int ty = t >> 5, tx = t & 31;  // t<256 active in tile phases
#pragma unroll 1
  for (int tile = 0; tile < 144; ++tile) {
    int tc = tile / 9, tp = tile - tc * 9;
    if (t < 256) {
#pragma unroll
      for (int r = 0; r < 4; ++r) {
        int cl = ty + r * 8;
        Lt[cl][tx] = src[(size_t)(tc * 32 + cl) * kHW + tp * 32 + tx];
      }
    }
    __syncthreads();
    if (t < 256) {
#pragma unroll
      for (int r = 0; r < 4; ++r) {
        int pl = ty + r * 8;
        int p  = tp * 32 + pl;
        dst[(size_t)p * kCQ + tc * 32 + tx] = f2bf(Lt[tx][pl] * inv[p]);
      }
    }
    __syncthreads();
  }
}

// -------- sim via MFMA + fused softmax --------
// grid (3 q-tiles of 96, 64 b), 512 thr (8 waves 2Mx4N). S[96][289] fp32 aliases As/Bs.
__global__ __launch_bounds__(512, 1) void sim_mfma_kernel(const unsigned short* __restrict__ fqT,
                                                          const unsigned short* __restrict__ fkT,
                                                          const int* __restrict__ idx,
                                                          unsigned short* __restrict__ prb) {
  __shared__ float Sbuf[96 * 289];  // 110976 B; As @0 (6KB), Bs @6144 (18KB) alias
  unsigned short* As = (unsigned short*)Sbuf;
  unsigned short* Bs = (unsigned short*)((char*)Sbuf + 6144);
  float (*S)[289] = (float(*)[289])Sbuf;
  int t    = threadIdx.x;
  int lane = t & 63;
  int wid  = t >> 6;
  int l15  = lane & 15, kg = lane >> 4;
  int wm   = wid & 1, wn = wid >> 1;  // 2M x 4N
  int q0   = blockIdx.x * 96;
  int b    = blockIdx.y;
  int tb   = idx[b];
  const unsigned short* fqb = fqT + ((size_t)b * kHW + q0) * kCQ;
  const unsigned short* fkb = fkT + (size_t)tb * kHW * kCQ;

  int aIdx[3];
#pragma unroll
  for (int fm = 0; fm < 3; ++fm) {
    int r = wm * 48 + fm * 16 + l15;
    aIdx[fm] = r * 32 + (kg ^ ((r ^ (r >> 2)) & 3)) * 8;
  }
  int nfn = (wn < 2) ? 5 : 4;
  int fnb = (wn < 2) ? wn * 5 : 10 + (wn - 2) * 4;
  int bIdx[5];
#pragma unroll
  for (int fi = 0; fi < 5; ++fi) {
    int kr = (fnb + fi) * 16 + l15;
    if (kr > 287) kr = 287;  // only unused frags
    bIdx[fi] = kr * 32 + (kg ^ ((kr ^ (kr >> 2)) & 3)) * 8;
  }

  f32x4 acc[3][5];
#pragma unroll
  for (int fm = 0; fm < 3; ++fm)
#pragma unroll
    for (int fi = 0; fi < 5; ++fi) acc[fm][fi] = (f32x4){0.f, 0.f, 0.f, 0.f};

#pragma unroll 1
  for (int chunk = 0; chunk < 16; ++chunk) {
    int c0 = chunk * 32;
    __syncthreads();  // prior chunk's frag reads done
    if (t < 384) {
      int ar = t >> 2, as = t & 3;
      ushort8 v = *(const ushort8*)(fqb + (size_t)ar * kCQ + c0 + as * 8);
      int slot = as ^ ((ar ^ (ar >> 2)) & 3);
      *(ushort8*)(As + ar * 32 + slot * 8) = v;
    }
#pragma unroll
    for (int i = 0; i < 3; ++i) {
      int item = i * 512 + t;
      if (item < 1152) {
        int kr = item >> 2, ks = item & 3;
        ushort8 v = *(const ushort8*)(fkb + (size_t)kr * kCQ + c0 + ks * 8);
        int slot = ks ^ ((kr ^ (kr >> 2)) & 3);
        *(ushort8*)(Bs + kr * 32 + slot * 8) = v;
      }
    }
    __syncthreads();
    bf16x8 a[3];
#pragma unroll
    for (int fm = 0; fm < 3; ++fm) a[fm] = *(const bf16x8*)(As + aIdx[fm]);
#pragma unroll
    for (int fi = 0; fi < 5; ++fi) {
      if (fi >= nfn) continue;  // wave-uniform
      bf16x8 bb = *(const bf16x8*)(Bs + bIdx[fi]);
#pragma unroll
      for (int fm = 0; fm < 3; ++fm)
        acc[fm][fi] = __builtin_amdgcn_mfma_f32_16x16x32_bf16(a[fm], bb, acc[fm][fi], 0, 0, 0);
    }
  }
  __syncthreads();  // all frag reads done before S overwrites As/Bs

  // write S: row q = wm*48+fm*16+kg*4+reg, col k = (fnb+fi)*16+l15
#pragma unroll
  for (int fm = 0; fm < 3; ++fm)
#pragma unroll
    for (int fi = 0; fi < 5; ++fi) {
      if (fi >= nfn) continue;
#pragma unroll
      for (int reg = 0; reg < 4; ++reg)
        S[wm * 48 + fm * 16 + kg * 4 + reg][(fnb + fi) * 16 + l15] = kTemp * acc[fm][fi][reg];
    }
  __syncthreads();

  // row softmax: wave w handles rows q = w, w+8, ...
  int l = lane;
  for (int q = wid; q < 96; q += 8) {
    float v[5];
    float m = -3.4e38f;
#pragma unroll
    for (int j = 0; j < 5; ++j) {
      int k = l + 64 * j;
      v[j] = (k < kHW) ? S[q][k] : -3.4e38f;
      m = fmaxf(m, v[j]);
    }
    for (int off = 32; off; off >>= 1) m = fmaxf(m, __shfl_xor(m, off));
    float e[5];
    float s = 0.f;
#pragma unroll
    for (int j = 0; j < 5; ++j) {
      int k = l + 64 * j;
      e[j] = (k < kHW) ? __expf(v[j] - m) : 0.f;
      s += e[j];
    }
    for (int off = 32; off; off >>= 1) s += __shfl_xor(s, off);
    float invs = 1.f / s;
    unsigned short* row = prb + ((size_t)b * kHW + q0 + q) * kHW;
#pragma unroll
    for (int j = 0; j < 5; ++j) {
      int k = l + 64 * j;
      if (k < kHW) row[k] = f2bf(e[j] * invs);
    }
  }
}

// -------- comask (reads bf16 pr) --------
__global__ __launch_bounds__(320) void comask_kernel(const unsigned short* __restrict__ prb,
                                                     const float* __restrict__ mask,
                                                     const int* __restrict__ idx,
                                                     float* __restrict__ comask) {
  int b = blockIdx.x;
  int t = threadIdx.x;
  int tb = idx[b];
  __shared__ float mt[kHW];
  __shared__ float cm[kHW];
  __shared__ float red[320];
  if (t < kHW) mt[t] = mask[tb * kHW + t];
  __syncthreads();
  int wv = t >> 6, l = t & 63;
  for (int q = wv; q < kHW; q += 5) {
    const unsigned short* prow = prb + ((size_t)b * kHW + q) * kHW;
    float s = 0.f;
    for (int k = l; k < kHW; k += 64) s += bf2f(prow[k]) * mt[k];
    for (int off = 32; off; off >>= 1) s += __shfl_xor(s, off);
    if (l == 0) cm[q] = mask[b * kHW + q] * s;
  }
  __syncthreads();
  float v = (t < kHW) ? cm[t] : 0.f;
  red[t] = (t < kHW) ? v : 3.4e38f;
  __syncthreads();
  float mn;
  {
    float m = 3.4e38f;
    if (t < 64) {
      for (int i = t; i < 320; i += 64) m = fminf(m, red[i]);
      for (int off = 32; off; off >>= 1) m = fminf(m, __shfl_xor(m, off));
    }
    __syncthreads();
    if (t == 0) red[0] = m;
    __syncthreads();
    mn = red[0];
    __syncthreads();
  }
  red[t] = (t < kHW) ? v : -3.4e38f;
  __syncthreads();
  float mx;
  {
    float m = -3.4e38f;
    if (t < 64) {
      for (int i = t; i < 320; i += 64) m = fmaxf(m, red[i]);
      for (int off = 32; off; off >>= 1) m = fmaxf(m, __shfl_xor(m, off));
    }
    __syncthreads();
    if (t == 0) red[0] = m;
    __syncthreads();
    mx = red[0];
  }
  if (t < kHW) comask[b * kHW + t] = (v - mn) / ((mx - mn) + 1e-12f);
}

// -------- triplet loss --------
__global__ __launch_bounds__(256) void loss_kernel(const float* __restrict__ dap,
                                                   const float* __restrict__ dan,
                                                   const float* __restrict__ comask,
                                                   float* __restrict__ out) {
  int t = threadIdx.x;
  float s = 0.f;
  for (int i = t; i < kB * kHW; i += 256) {
    float da = sqrtf(dap[i]);
    float db = sqrtf(dan[i]);
    float tr = fmaxf(da - db + 0.3f, 0.f);
    s += comask[i] * tr;
  }
  for (int off = 32; off; off >>= 1) s += __shfl_xor(s, off);
  __shared__ float sh[4];
  if ((t & 63) == 0) sh[t >> 6] = s;
  __syncthreads();
  if (t == 0)
    out[(size_t)kB * kC * kHW] = (sh[0] + sh[1] + sh[2] + sh[3]) * (1.f / (float)(kB * kHW));
}

extern "C" void kernel_launch(void* const* d_in, const int* in_sizes, int n_in,
                              void* d_out, int out_size, void* d_ws, size_t ws_size,
                              hipStream_t stream) {
  const float* fv = (const float*)d_in[0];
  const float* ft = (const float*)d_in[1];
  const float* qw = (const float*)d_in[4];
  const float* qb = (const float*)d_in[5];
  const float* kw = (const float*)d_in[6];
  const float* kb = (const float*)d_in[7];
  const int* pos_idx = (const int*)d_in[8];
  const int* neg_idx = (const int*)d_in[9];
  float* out = (float*)d_out;

  // ws: fq 37.75M | fk 37.75M | region3 37.75M | small 0.44M
  // region3: wt (prep/conv) -> fqT+fkT (exactly 37.75M) after conv.
  // prb (10.6M bf16) aliases fq region (fp32 fq dead after norm_transpose).
  constexpr size_t kFQ = (size_t)kB * kCQ * kHW;
  float* ws   = (float*)d_ws;
  float* fq   = ws;
  float* fk   = fq + kFQ;
  unsigned short* wtq = (unsigned short*)(fk + kFQ);
  unsigned short* wtk = wtq + (size_t)9 * kCQ * kC;
  unsigned short* fqT = wtq;                               // alias region3
  unsigned short* fkT = fqT + (size_t)kB * kHW * kCQ;
  unsigned short* prb = (unsigned short*)fq;               // alias fq (dead after transpose)
  float* part = (float*)wtq;                               // alias: mask partials, dead before prep_w
  float* maskb   = (float*)(wtk + (size_t)9 * kCQ * kC);
  float* qinv    = maskb + kB * kHW;   // unused slots kept for layout stability
  float* kinv    = qinv + kB * kHW;
  float* comaskb = kinv + kB * kHW;
  float* dap     = comaskb + kB * kHW;
  float* dan     = dap + kB * kHW;
  (void)qinv; (void)kinv;
  if (ws_size < (size_t)113688576) return;

  zero_kernel<<<dim3((2 * kB * kHW + 255) / 256), 256, 0, stream>>>(dap, 2 * kB * kHW);
  mask_part_kernel<<<dim3(kB, 4), 320, 0, stream>>>(fv, ft, part);
  mask_fin_kernel<<<dim3(kB), 320, 0, stream>>>(part, maskb);
  prep_w_kernel<<<dim3(kCQ, 2), 256, 0, stream>>>(qw, kw, wtq, wtk);
  conv_fused_kernel<<<dim3(256), 512, 0, stream>>>(wtq, wtk, qb, kb, fv, ft, fq, fk);
  norm_transpose_kernel<<<dim3(kB, 2), 320, 0, stream>>>(fq, fk, fqT, fkT);

  // positive branch
  sim_mfma_kernel<<<dim3(3, kB), 512, 0, stream>>>(fqT, fkT, pos_idx, prb);
  comask_kernel<<<dim3(kB), 320, 0, stream>>>(prb, maskb, pos_idx, comaskb);
  warp_mfma_kernel<<<dim3(16, kB), 512, 0, stream>>>(fv, ft, prb, maskb, pos_idx, out, dap, 1);

  // negative branch
  sim_mfma_kernel<<<dim3(3, kB), 512, 0, stream>>>(fqT, fkT, neg_idx, prb);
  warp_mfma_kernel<<<dim3(16, kB), 512, 0, stream>>>(fv, ft, prb, maskb, neg_idx, out, dan, 0);

  loss_kernel<<<dim3(1), 256, 0, stream>>>(dap, dan, comaskb, out);
}